// Round 1
// baseline (1710.135 us; speedup 1.0000x reference)
//
#include <hip/hip_runtime.h>
#include <hip/hip_bf16.h>
#include <cstdint>

#define B_ 2
#define S_ 2048
#define E_ 2048
#define H_ 32
#define KVH_ 8
#define D_ 64

typedef __bf16 bf16;
typedef __bf16 bf16x4 __attribute__((ext_vector_type(4)));
typedef __bf16 bf16x8 __attribute__((ext_vector_type(8)));
typedef float f32x4 __attribute__((ext_vector_type(4)));

// ---------------- cast x (f32) -> bf16 ----------------
__global__ __launch_bounds__(256) void cast_f32_bf16_k(const float* __restrict__ src,
                                                       bf16* __restrict__ dst, int n) {
    int i = (blockIdx.x * 256 + threadIdx.x) * 4;
    if (i < n) {
        f32x4 v = *(const f32x4*)(src + i);
        bf16x4 o;
        o[0] = (bf16)v[0]; o[1] = (bf16)v[1]; o[2] = (bf16)v[2]; o[3] = (bf16)v[3];
        *(bf16x4*)(dst + i) = o;
    }
}

// ---------------- transpose + cast: src f32 [R][C] -> dst bf16 [C][R], R==2048 ----------------
__global__ __launch_bounds__(256) void transpose_cast_k(const float* __restrict__ src,
                                                        bf16* __restrict__ dst, int C) {
    __shared__ float tile[32][33];
    int c0 = blockIdx.x * 32, r0 = blockIdx.y * 32;
    int tx = threadIdx.x, ty = threadIdx.y;  // (32, 8)
#pragma unroll
    for (int i = 0; i < 4; i++)
        tile[ty + 8 * i][tx] = src[(size_t)(r0 + ty + 8 * i) * C + c0 + tx];
    __syncthreads();
#pragma unroll
    for (int i = 0; i < 4; i++)
        dst[(size_t)(c0 + ty + 8 * i) * 2048 + r0 + tx] = (bf16)tile[tx][ty + 8 * i];
}

// ---------------- RoPE cos/sin table: tbl[(s*32+dp)*2] = {cos, sin} ----------------
__global__ __launch_bounds__(256) void rope_table_k(float* __restrict__ tbl) {
    int t = blockIdx.x * 256 + threadIdx.x;  // S_*32 threads
    int dp = t & 31, s = t >> 5;
    float invf = exp2f(-(float)dp * (13.287712379549449f / 32.0f));  // 10000^(-dp/32)
    float ang = (float)s * invf;
    tbl[t * 2] = cosf(ang);
    tbl[t * 2 + 1] = sinf(ang);
}

// ---------------- RoPE apply in-place on bf16 [B][NH][S][64] ----------------
__global__ __launch_bounds__(256) void rope_apply_k(bf16* __restrict__ T,
                                                    const float* __restrict__ tbl, int total) {
    int t = blockIdx.x * 256 + threadIdx.x;
    if (t >= total) return;
    int dp = t & 31;
    int s = (t >> 5) & (S_ - 1);
    int bh = t >> 16;  // 32*2048 = 2^16
    size_t base = ((size_t)bh * S_ + s) * D_ + dp;
    float c = tbl[(s * 32 + dp) * 2], sn = tbl[(s * 32 + dp) * 2 + 1];
    float v1 = (float)T[base], v2 = (float)T[base + 32];
    T[base] = (bf16)(v1 * c - v2 * sn);
    T[base + 32] = (bf16)(v1 * sn + v2 * c);
}

// ---------------- bf16 MFMA GEMM: C[M][N] = A[M][2048] * Bt[N][2048]^T ----------------
// 128x128 tile, BK=32, 4 waves (2x2), each wave 64x64 (4x4 frags of 16x16x32).
// MODE 0: scatter-store bf16 into Q [B][H][S][D] / K,V [B][KVH][S][D] (n regions).
// MODE 1: store f32 to Cf [M][2048].
template <int MODE>
__global__ __launch_bounds__(256) void gemm_bf16_k(const bf16* __restrict__ A,
                                                   const bf16* __restrict__ Bt,
                                                   bf16* __restrict__ Q, bf16* __restrict__ Kb,
                                                   bf16* __restrict__ Vb, float* __restrict__ Cf) {
    __shared__ bf16 As[128 * 40];  // pad 32->40 shorts/row (80B stride) to break conflicts
    __shared__ bf16 Bs[128 * 40];
    const int t = threadIdx.x;
    const int lane = t & 63, w = t >> 6;
    const int wm = w >> 1, wn = w & 1;
    const int g = lane >> 4, l15 = lane & 15;
    const int m0 = blockIdx.y * 128, n0 = blockIdx.x * 128;

    f32x4 acc[4][4];
#pragma unroll
    for (int i = 0; i < 4; i++)
#pragma unroll
        for (int j = 0; j < 4; j++) acc[i][j] = f32x4{0.f, 0.f, 0.f, 0.f};

    const int c0 = t, c1 = t + 256;
    const int ar0 = c0 >> 2, ak0 = (c0 & 3) * 8;
    const int ar1 = c1 >> 2, ak1 = (c1 & 3) * 8;

    for (int k0 = 0; k0 < 2048; k0 += 32) {
        bf16x8 a0 = *(const bf16x8*)(A + (size_t)(m0 + ar0) * 2048 + k0 + ak0);
        bf16x8 a1 = *(const bf16x8*)(A + (size_t)(m0 + ar1) * 2048 + k0 + ak1);
        bf16x8 b0 = *(const bf16x8*)(Bt + (size_t)(n0 + ar0) * 2048 + k0 + ak0);
        bf16x8 b1 = *(const bf16x8*)(Bt + (size_t)(n0 + ar1) * 2048 + k0 + ak1);
        __syncthreads();
        *(bf16x8*)(As + ar0 * 40 + ak0) = a0;
        *(bf16x8*)(As + ar1 * 40 + ak1) = a1;
        *(bf16x8*)(Bs + ar0 * 40 + ak0) = b0;
        *(bf16x8*)(Bs + ar1 * 40 + ak1) = b1;
        __syncthreads();
        bf16x8 af[4], bfr[4];
#pragma unroll
        for (int i = 0; i < 4; i++) {
            af[i] = *(const bf16x8*)(As + (wm * 64 + i * 16 + l15) * 40 + g * 8);
            bfr[i] = *(const bf16x8*)(Bs + (wn * 64 + i * 16 + l15) * 40 + g * 8);
        }
#pragma unroll
        for (int i = 0; i < 4; i++)
#pragma unroll
            for (int j = 0; j < 4; j++)
                acc[i][j] = __builtin_amdgcn_mfma_f32_16x16x32_bf16(af[i], bfr[j], acc[i][j], 0, 0, 0);
    }

#pragma unroll
    for (int i = 0; i < 4; i++) {
        int mB = m0 + wm * 64 + i * 16 + g * 4;
        int b = mB >> 11, s = mB & 2047;
#pragma unroll
        for (int j = 0; j < 4; j++) {
            int n = n0 + wn * 64 + j * 16 + l15;
            f32x4 v = acc[i][j];
            if constexpr (MODE == 0) {
                bf16* dst;
                if (n < 2048)
                    dst = Q + (((size_t)b * H_ + (n >> 6)) * S_ + s) * D_ + (n & 63);
                else if (n < 2560)
                    dst = Kb + (((size_t)b * KVH_ + ((n - 2048) >> 6)) * S_ + s) * D_ + (n & 63);
                else
                    dst = Vb + (((size_t)b * KVH_ + ((n - 2560) >> 6)) * S_ + s) * D_ + (n & 63);
#pragma unroll
                for (int r = 0; r < 4; r++) dst[r * 64] = (bf16)v[r];
            } else {
#pragma unroll
                for (int r = 0; r < 4; r++) Cf[(size_t)(mB + r) * 2048 + n] = v[r];
            }
        }
    }
}

// ---------------- fp32 flash attention (causal, GQA) ----------------
// block = (qc, h, b); 256 thr: row r=t>>2 (64 q rows), part p=t&3 (16 dims each).
__global__ __launch_bounds__(256) void attn_k(const bf16* __restrict__ Q,
                                              const bf16* __restrict__ Kb,
                                              const bf16* __restrict__ Vb,
                                              bf16* __restrict__ Out) {
    __shared__ float Ks[64][64];
    __shared__ float Vs[64][64];
    const int t = threadIdx.x;
    const int qc = blockIdx.x, h = blockIdx.y, b = blockIdx.z;
    const int kvh = h >> 2;
    const int r = t >> 2, p = t & 3;
    const int s_q = qc * 64 + r;

    const bf16* qptr = Q + (((size_t)b * H_ + h) * S_ + s_q) * D_ + p * 16;
    float q[16];
    {
        bf16x8 q0 = *(const bf16x8*)(qptr);
        bf16x8 q1 = *(const bf16x8*)(qptr + 8);
#pragma unroll
        for (int i = 0; i < 8; i++) { q[i] = (float)q0[i]; q[8 + i] = (float)q1[i]; }
    }
    const bf16* kbase = Kb + ((size_t)b * KVH_ + kvh) * (size_t)S_ * D_;
    const bf16* vbase = Vb + ((size_t)b * KVH_ + kvh) * (size_t)S_ * D_;

    float m = -1e30f, l = 0.f, O[16];
#pragma unroll
    for (int i = 0; i < 16; i++) O[i] = 0.f;
    const float SC = 0.125f * 1.4426950408889634f;  // 1/sqrt(D) * log2(e)

    for (int j0 = 0; j0 <= qc * 64; j0 += 64) {
        bf16x8 k0v = *(const bf16x8*)(kbase + (size_t)(j0 + r) * 64 + p * 16);
        bf16x8 k1v = *(const bf16x8*)(kbase + (size_t)(j0 + r) * 64 + p * 16 + 8);
        bf16x8 v0v = *(const bf16x8*)(vbase + (size_t)(j0 + r) * 64 + p * 16);
        bf16x8 v1v = *(const bf16x8*)(vbase + (size_t)(j0 + r) * 64 + p * 16 + 8);
        __syncthreads();
#pragma unroll
        for (int i = 0; i < 8; i++) {
            Ks[r][p * 16 + i] = (float)k0v[i];
            Ks[r][p * 16 + 8 + i] = (float)k1v[i];
            Vs[r][p * 16 + i] = (float)v0v[i];
            Vs[r][p * 16 + 8 + i] = (float)v1v[i];
        }
        __syncthreads();
        int jmax = min(63, s_q - j0);
        for (int jj = 0; jj <= jmax; jj++) {
            const float* krow = &Ks[jj][p * 16];
            float sdot = 0.f;
#pragma unroll
            for (int i = 0; i < 16; i++) sdot += q[i] * krow[i];
            sdot += __shfl_xor(sdot, 1);
            sdot += __shfl_xor(sdot, 2);
            sdot *= SC;
            float mn = fmaxf(m, sdot);
            if (mn > m) {  // rescale only when max moves
                float corr = exp2f(m - mn);
                l *= corr;
#pragma unroll
                for (int i = 0; i < 16; i++) O[i] *= corr;
                m = mn;
            }
            float pr = exp2f(sdot - m);
            l += pr;
            const float* vrow = &Vs[jj][p * 16];
#pragma unroll
            for (int i = 0; i < 16; i++) O[i] += pr * vrow[i];
        }
    }
    float inv = 1.f / l;
    bf16* optr = Out + ((size_t)(b * S_ + s_q)) * 2048 + h * 64 + p * 16;
#pragma unroll
    for (int i = 0; i < 16; i++) optr[i] = (bf16)(O[i] * inv);
}

extern "C" void kernel_launch(void* const* d_in, const int* in_sizes, int n_in,
                              void* d_out, int out_size, void* d_ws, size_t ws_size,
                              hipStream_t stream) {
    const float* x = (const float*)d_in[0];
    const float* Wq = (const float*)d_in[1];
    const float* Wk = (const float*)d_in[2];
    const float* Wv = (const float*)d_in[3];
    const float* Wo = (const float*)d_in[4];
    float* out = (float*)d_out;

    char* ws = (char*)d_ws;
    size_t off = 0;
    auto alloc = [&](size_t bytes) {
        void* p = ws + off;
        off += (bytes + 255) & ~(size_t)255;
        return p;
    };
    bf16* xb = (bf16*)alloc((size_t)4096 * 2048 * 2);
    bf16* WqkvT = (bf16*)alloc((size_t)3072 * 2048 * 2);
    bf16* WoT = (bf16*)alloc((size_t)2048 * 2048 * 2);
    bf16* Qb = (bf16*)alloc((size_t)B_ * H_ * S_ * D_ * 2);
    bf16* Kb = (bf16*)alloc((size_t)B_ * KVH_ * S_ * D_ * 2);
    bf16* Vb = (bf16*)alloc((size_t)B_ * KVH_ * S_ * D_ * 2);
    float* tbl = (float*)alloc((size_t)S_ * 32 * 2 * sizeof(float));
    bf16* attn = xb;  // alias: xb is dead after gemm_qkv, attn written later

    cast_f32_bf16_k<<<8192, 256, 0, stream>>>(x, xb, 4096 * 2048);
    dim3 tb(32, 8);
    transpose_cast_k<<<dim3(64, 64), tb, 0, stream>>>(Wq, WqkvT, 2048);
    transpose_cast_k<<<dim3(16, 64), tb, 0, stream>>>(Wk, WqkvT + (size_t)2048 * 2048, 512);
    transpose_cast_k<<<dim3(16, 64), tb, 0, stream>>>(Wv, WqkvT + (size_t)2560 * 2048, 512);
    transpose_cast_k<<<dim3(64, 64), tb, 0, stream>>>(Wo, WoT, 2048);
    rope_table_k<<<256, 256, 0, stream>>>(tbl);

    gemm_bf16_k<0><<<dim3(24, 32), 256, 0, stream>>>(xb, WqkvT, Qb, Kb, Vb, nullptr);

    rope_apply_k<<<16384, 256, 0, stream>>>(Qb, tbl, B_ * H_ * S_ * 32);
    rope_apply_k<<<4096, 256, 0, stream>>>(Kb, tbl, B_ * KVH_ * S_ * 32);

    attn_k<<<dim3(S_ / 64, H_, B_), 256, 0, stream>>>(Qb, Kb, Vb, attn);

    gemm_bf16_k<1><<<dim3(16, 32), 256, 0, stream>>>(attn, WoT, nullptr, nullptr, nullptr, out);
}

// Round 2
// 424.851 us; speedup vs baseline: 4.0253x; 4.0253x over previous
//
#include <hip/hip_runtime.h>
#include <hip/hip_bf16.h>
#include <cstdint>

#define B_ 2
#define S_ 2048
#define E_ 2048
#define H_ 32
#define KVH_ 8
#define D_ 64

typedef __bf16 bf16;
typedef __bf16 bf16x4 __attribute__((ext_vector_type(4)));
typedef __bf16 bf16x8 __attribute__((ext_vector_type(8)));
typedef float f32x4 __attribute__((ext_vector_type(4)));

// ---------------- cast x (f32) -> bf16 ----------------
__global__ __launch_bounds__(256) void cast_f32_bf16_k(const float* __restrict__ src,
                                                       bf16* __restrict__ dst, int n) {
    int i = (blockIdx.x * 256 + threadIdx.x) * 4;
    if (i < n) {
        f32x4 v = *(const f32x4*)(src + i);
        bf16x4 o;
        o[0] = (bf16)v[0]; o[1] = (bf16)v[1]; o[2] = (bf16)v[2]; o[3] = (bf16)v[3];
        *(bf16x4*)(dst + i) = o;
    }
}

// ---------------- transpose + cast: src f32 [R][C] -> dst bf16 [C][R], R==2048 ----------------
__global__ __launch_bounds__(256) void transpose_cast_k(const float* __restrict__ src,
                                                        bf16* __restrict__ dst, int C) {
    __shared__ float tile[32][33];
    int c0 = blockIdx.x * 32, r0 = blockIdx.y * 32;
    int tx = threadIdx.x, ty = threadIdx.y;  // (32, 8)
#pragma unroll
    for (int i = 0; i < 4; i++)
        tile[ty + 8 * i][tx] = src[(size_t)(r0 + ty + 8 * i) * C + c0 + tx];
    __syncthreads();
#pragma unroll
    for (int i = 0; i < 4; i++)
        dst[(size_t)(c0 + ty + 8 * i) * 2048 + r0 + tx] = (bf16)tile[tx][ty + 8 * i];
}

// ---------------- RoPE cos/sin table: tbl[(s*32+dp)*2] = {cos, sin} ----------------
__global__ __launch_bounds__(256) void rope_table_k(float* __restrict__ tbl) {
    int t = blockIdx.x * 256 + threadIdx.x;  // S_*32 threads
    int dp = t & 31, s = t >> 5;
    float invf = exp2f(-(float)dp * (13.287712379549449f / 32.0f));  // 10000^(-dp/32)
    float ang = (float)s * invf;
    tbl[t * 2] = cosf(ang);
    tbl[t * 2 + 1] = sinf(ang);
}

// ---------------- RoPE apply in-place on bf16 [B][NH][S][64] ----------------
__global__ __launch_bounds__(256) void rope_apply_k(bf16* __restrict__ T,
                                                    const float* __restrict__ tbl, int total) {
    int t = blockIdx.x * 256 + threadIdx.x;
    if (t >= total) return;
    int dp = t & 31;
    int s = (t >> 5) & (S_ - 1);
    int bh = t >> 16;  // 32*2048 = 2^16
    size_t base = ((size_t)bh * S_ + s) * D_ + dp;
    float c = tbl[(s * 32 + dp) * 2], sn = tbl[(s * 32 + dp) * 2 + 1];
    float v1 = (float)T[base], v2 = (float)T[base + 32];
    T[base] = (bf16)(v1 * c - v2 * sn);
    T[base + 32] = (bf16)(v1 * sn + v2 * c);
}

// ---------------- bf16 MFMA GEMM: C[M][N] = A[M][2048] * Bt[N][2048]^T ----------------
template <int MODE>
__global__ __launch_bounds__(256) void gemm_bf16_k(const bf16* __restrict__ A,
                                                   const bf16* __restrict__ Bt,
                                                   bf16* __restrict__ Q, bf16* __restrict__ Kb,
                                                   bf16* __restrict__ Vb, float* __restrict__ Cf) {
    __shared__ bf16 As[128 * 40];
    __shared__ bf16 Bs[128 * 40];
    const int t = threadIdx.x;
    const int lane = t & 63, w = t >> 6;
    const int wm = w >> 1, wn = w & 1;
    const int g = lane >> 4, l15 = lane & 15;
    const int m0 = blockIdx.y * 128, n0 = blockIdx.x * 128;

    f32x4 acc[4][4];
#pragma unroll
    for (int i = 0; i < 4; i++)
#pragma unroll
        for (int j = 0; j < 4; j++) acc[i][j] = f32x4{0.f, 0.f, 0.f, 0.f};

    const int c0 = t, c1 = t + 256;
    const int ar0 = c0 >> 2, ak0 = (c0 & 3) * 8;
    const int ar1 = c1 >> 2, ak1 = (c1 & 3) * 8;

    for (int k0 = 0; k0 < 2048; k0 += 32) {
        bf16x8 a0 = *(const bf16x8*)(A + (size_t)(m0 + ar0) * 2048 + k0 + ak0);
        bf16x8 a1 = *(const bf16x8*)(A + (size_t)(m0 + ar1) * 2048 + k0 + ak1);
        bf16x8 b0 = *(const bf16x8*)(Bt + (size_t)(n0 + ar0) * 2048 + k0 + ak0);
        bf16x8 b1 = *(const bf16x8*)(Bt + (size_t)(n0 + ar1) * 2048 + k0 + ak1);
        __syncthreads();
        *(bf16x8*)(As + ar0 * 40 + ak0) = a0;
        *(bf16x8*)(As + ar1 * 40 + ak1) = a1;
        *(bf16x8*)(Bs + ar0 * 40 + ak0) = b0;
        *(bf16x8*)(Bs + ar1 * 40 + ak1) = b1;
        __syncthreads();
        bf16x8 af[4], bfr[4];
#pragma unroll
        for (int i = 0; i < 4; i++) {
            af[i] = *(const bf16x8*)(As + (wm * 64 + i * 16 + l15) * 40 + g * 8);
            bfr[i] = *(const bf16x8*)(Bs + (wn * 64 + i * 16 + l15) * 40 + g * 8);
        }
#pragma unroll
        for (int i = 0; i < 4; i++)
#pragma unroll
            for (int j = 0; j < 4; j++)
                acc[i][j] = __builtin_amdgcn_mfma_f32_16x16x32_bf16(af[i], bfr[j], acc[i][j], 0, 0, 0);
    }

#pragma unroll
    for (int i = 0; i < 4; i++) {
        int mB = m0 + wm * 64 + i * 16 + g * 4;
        int b = mB >> 11, s = mB & 2047;
#pragma unroll
        for (int j = 0; j < 4; j++) {
            int n = n0 + wn * 64 + j * 16 + l15;
            f32x4 v = acc[i][j];
            if constexpr (MODE == 0) {
                bf16* dst;
                if (n < 2048)
                    dst = Q + (((size_t)b * H_ + (n >> 6)) * S_ + s) * D_ + (n & 63);
                else if (n < 2560)
                    dst = Kb + (((size_t)b * KVH_ + ((n - 2048) >> 6)) * S_ + s) * D_ + (n & 63);
                else
                    dst = Vb + (((size_t)b * KVH_ + ((n - 2560) >> 6)) * S_ + s) * D_ + (n & 63);
#pragma unroll
                for (int r = 0; r < 4; r++) dst[r * 64] = (bf16)v[r];
            } else {
#pragma unroll
                for (int r = 0; r < 4; r++) Cf[(size_t)(mB + r) * 2048 + n] = v[r];
            }
        }
    }
}

// ---------------- MFMA flash attention (causal, GQA) ----------------
// Block: 4 waves, 128 q-rows of one (b,h). KV tile = 64.
// K_lds [64][72] row-major [k][d]; Vt_lds [64][72] = V^T [d][k]; P_lds [128][72].
// Frags: 16x16x32 bf16; A/B lane (g,l15) holds [l15][8g..8g+7]; C lane holds rows g*4+r, col l15.
__global__ __launch_bounds__(256) void attn_mfma_k(const bf16* __restrict__ Q,
                                                   const bf16* __restrict__ Kb,
                                                   const bf16* __restrict__ Vb,
                                                   bf16* __restrict__ Out) {
    __shared__ bf16 Ks[64 * 72];
    __shared__ bf16 Vt[64 * 72];
    __shared__ bf16 Ps[128 * 72];
    const int t = threadIdx.x;
    const int w = t >> 6, lane = t & 63, g = lane >> 4, l15 = lane & 15;
    const int h = blockIdx.y, b = blockIdx.z;
    const int kvh = h >> 2;
    const int q0 = blockIdx.x * 128;
    const int qw = q0 + w * 32;

    const bf16* qbase = Q + ((size_t)b * H_ + h) * (size_t)S_ * D_;
    const bf16* kbase = Kb + ((size_t)b * KVH_ + kvh) * (size_t)S_ * D_;
    const bf16* vbase = Vb + ((size_t)b * KVH_ + kvh) * (size_t)S_ * D_;

    // Q fragments (held in registers for the whole kernel)
    bf16x8 qf[2][2];
#pragma unroll
    for (int mf = 0; mf < 2; mf++)
#pragma unroll
        for (int ks = 0; ks < 2; ks++)
            qf[mf][ks] = *(const bf16x8*)(qbase + (size_t)(qw + mf * 16 + l15) * 64 + ks * 32 + g * 8);

    f32x4 accO[2][4];
    float m_[2][4], l_[2][4];
#pragma unroll
    for (int mf = 0; mf < 2; mf++) {
#pragma unroll
        for (int nf = 0; nf < 4; nf++) accO[mf][nf] = f32x4{0.f, 0.f, 0.f, 0.f};
#pragma unroll
        for (int r = 0; r < 4; r++) { m_[mf][r] = -1e30f; l_[mf][r] = 0.f; }
    }

    const float SC = 0.18033688011112042f;  // log2(e)/8

    for (int j0 = 0; j0 < q0 + 128; j0 += 64) {
        __syncthreads();
        // --- stage K tile: 64x64, unit u: row=u>>3, ch=u&7 (8 bf16 per unit)
        {
            int row0 = t >> 3, ch0 = t & 7;
            bf16x8 kv0 = *(const bf16x8*)(kbase + (size_t)(j0 + row0) * 64 + ch0 * 8);
            *(bf16x8*)(Ks + row0 * 72 + ch0 * 8) = kv0;
            int u1 = t + 256;
            int row1 = u1 >> 3, ch1 = u1 & 7;
            bf16x8 kv1 = *(const bf16x8*)(kbase + (size_t)(j0 + row1) * 64 + ch1 * 8);
            *(bf16x8*)(Ks + row1 * 72 + ch1 * 8) = kv1;
        }
        // --- stage V transposed: thread handles k=t&63, d-block (t>>6)*16
        {
            int k = t & 63, d0 = (t >> 6) * 16;
            bf16x8 v0 = *(const bf16x8*)(vbase + (size_t)(j0 + k) * 64 + d0);
            bf16x8 v1 = *(const bf16x8*)(vbase + (size_t)(j0 + k) * 64 + d0 + 8);
#pragma unroll
            for (int e = 0; e < 8; e++) {
                Vt[(d0 + e) * 72 + k] = v0[e];
                Vt[(d0 + 8 + e) * 72 + k] = v1[e];
            }
        }
        __syncthreads();

        // --- QK^T
        bf16x8 kf[4][2];
#pragma unroll
        for (int nf = 0; nf < 4; nf++)
#pragma unroll
            for (int ks = 0; ks < 2; ks++)
                kf[nf][ks] = *(const bf16x8*)(Ks + (nf * 16 + l15) * 72 + ks * 32 + g * 8);
        f32x4 sc[2][4];
#pragma unroll
        for (int mf = 0; mf < 2; mf++)
#pragma unroll
            for (int nf = 0; nf < 4; nf++) {
                sc[mf][nf] = f32x4{0.f, 0.f, 0.f, 0.f};
#pragma unroll
                for (int ks = 0; ks < 2; ks++)
                    sc[mf][nf] = __builtin_amdgcn_mfma_f32_16x16x32_bf16(qf[mf][ks], kf[nf][ks],
                                                                         sc[mf][nf], 0, 0, 0);
            }

        const bool diag = (j0 + 63 > q0);  // any lane may need masking
        const int kcol = j0 + l15;         // + nf*16
        // --- online softmax (per mf; lane rows = g*4+r)
#pragma unroll
        for (int mf = 0; mf < 2; mf++) {
            int srow = qw + mf * 16 + g * 4;
            float sv[4][4];  // [nf][r]
#pragma unroll
            for (int nf = 0; nf < 4; nf++)
#pragma unroll
                for (int r = 0; r < 4; r++) {
                    float v = sc[mf][nf][r] * SC;
                    if (diag && (kcol + nf * 16 > srow + r)) v = -1e30f;
                    sv[nf][r] = v;
                }
            float rmax[4];
#pragma unroll
            for (int r = 0; r < 4; r++) {
                rmax[r] = fmaxf(fmaxf(sv[0][r], sv[1][r]), fmaxf(sv[2][r], sv[3][r]));
                rmax[r] = fmaxf(rmax[r], __shfl_xor(rmax[r], 1));
                rmax[r] = fmaxf(rmax[r], __shfl_xor(rmax[r], 2));
                rmax[r] = fmaxf(rmax[r], __shfl_xor(rmax[r], 4));
                rmax[r] = fmaxf(rmax[r], __shfl_xor(rmax[r], 8));
            }
#pragma unroll
            for (int r = 0; r < 4; r++) {
                float mn = fmaxf(m_[mf][r], rmax[r]);
                float corr = exp2f(m_[mf][r] - mn);
                m_[mf][r] = mn;
                l_[mf][r] *= corr;
#pragma unroll
                for (int nf = 0; nf < 4; nf++) accO[mf][nf][r] *= corr;
            }
            float rsum[4] = {0.f, 0.f, 0.f, 0.f};
#pragma unroll
            for (int nf = 0; nf < 4; nf++)
#pragma unroll
                for (int r = 0; r < 4; r++) {
                    float p = exp2f(sv[nf][r] - m_[mf][r]);
                    rsum[r] += p;
                    Ps[(w * 32 + mf * 16 + g * 4 + r) * 72 + nf * 16 + l15] = (bf16)p;
                }
#pragma unroll
            for (int r = 0; r < 4; r++) {
                float s = rsum[r];
                s += __shfl_xor(s, 1);
                s += __shfl_xor(s, 2);
                s += __shfl_xor(s, 4);
                s += __shfl_xor(s, 8);
                l_[mf][r] += s;
            }
        }

        // --- PV (each wave reads only its own P rows; same-wave ds ordering suffices)
        bf16x8 vf[4][2];
#pragma unroll
        for (int nf = 0; nf < 4; nf++)
#pragma unroll
            for (int ks = 0; ks < 2; ks++)
                vf[nf][ks] = *(const bf16x8*)(Vt + (nf * 16 + l15) * 72 + ks * 32 + g * 8);
#pragma unroll
        for (int mf = 0; mf < 2; mf++)
#pragma unroll
            for (int ks = 0; ks < 2; ks++) {
                bf16x8 pa = *(const bf16x8*)(Ps + (w * 32 + mf * 16 + l15) * 72 + ks * 32 + g * 8);
#pragma unroll
                for (int nf = 0; nf < 4; nf++)
                    accO[mf][nf] = __builtin_amdgcn_mfma_f32_16x16x32_bf16(pa, vf[nf][ks],
                                                                           accO[mf][nf], 0, 0, 0);
            }
    }

    // --- epilogue: normalize, store bf16 to [b*S+s][h*64+d]
#pragma unroll
    for (int mf = 0; mf < 2; mf++) {
        float inv[4];
#pragma unroll
        for (int r = 0; r < 4; r++) inv[r] = 1.f / l_[mf][r];
#pragma unroll
        for (int nf = 0; nf < 4; nf++) {
#pragma unroll
            for (int r = 0; r < 4; r++) {
                int srow = qw + mf * 16 + g * 4 + r;
                Out[((size_t)(b * S_ + srow)) * 2048 + h * 64 + nf * 16 + l15] =
                    (bf16)(accO[mf][nf][r] * inv[r]);
            }
        }
    }
}

extern "C" void kernel_launch(void* const* d_in, const int* in_sizes, int n_in,
                              void* d_out, int out_size, void* d_ws, size_t ws_size,
                              hipStream_t stream) {
    const float* x = (const float*)d_in[0];
    const float* Wq = (const float*)d_in[1];
    const float* Wk = (const float*)d_in[2];
    const float* Wv = (const float*)d_in[3];
    const float* Wo = (const float*)d_in[4];
    float* out = (float*)d_out;

    char* ws = (char*)d_ws;
    size_t off = 0;
    auto alloc = [&](size_t bytes) {
        void* p = ws + off;
        off += (bytes + 255) & ~(size_t)255;
        return p;
    };
    bf16* xb = (bf16*)alloc((size_t)4096 * 2048 * 2);
    bf16* WqkvT = (bf16*)alloc((size_t)3072 * 2048 * 2);
    bf16* WoT = (bf16*)alloc((size_t)2048 * 2048 * 2);
    bf16* Qb = (bf16*)alloc((size_t)B_ * H_ * S_ * D_ * 2);
    bf16* Kb = (bf16*)alloc((size_t)B_ * KVH_ * S_ * D_ * 2);
    bf16* Vb = (bf16*)alloc((size_t)B_ * KVH_ * S_ * D_ * 2);
    float* tbl = (float*)alloc((size_t)S_ * 32 * 2 * sizeof(float));
    bf16* attn = xb;  // alias: xb dead after QKV GEMM

    cast_f32_bf16_k<<<8192, 256, 0, stream>>>(x, xb, 4096 * 2048);
    dim3 tb(32, 8);
    transpose_cast_k<<<dim3(64, 64), tb, 0, stream>>>(Wq, WqkvT, 2048);
    transpose_cast_k<<<dim3(16, 64), tb, 0, stream>>>(Wk, WqkvT + (size_t)2048 * 2048, 512);
    transpose_cast_k<<<dim3(16, 64), tb, 0, stream>>>(Wv, WqkvT + (size_t)2560 * 2048, 512);
    transpose_cast_k<<<dim3(64, 64), tb, 0, stream>>>(Wo, WoT, 2048);
    rope_table_k<<<256, 256, 0, stream>>>(tbl);

    gemm_bf16_k<0><<<dim3(24, 32), 256, 0, stream>>>(xb, WqkvT, Qb, Kb, Vb, nullptr);

    rope_apply_k<<<16384, 256, 0, stream>>>(Qb, tbl, B_ * H_ * S_ * 32);
    rope_apply_k<<<4096, 256, 0, stream>>>(Kb, tbl, B_ * KVH_ * S_ * 32);

    attn_mfma_k<<<dim3(S_ / 128, H_, B_), 256, 0, stream>>>(Qb, Kb, Vb, attn);

    gemm_bf16_k<1><<<dim3(16, 32), 256, 0, stream>>>(attn, WoT, nullptr, nullptr, nullptr, out);
}

// Round 3
// 327.765 us; speedup vs baseline: 5.2176x; 1.2962x over previous
//
#include <hip/hip_runtime.h>
#include <hip/hip_bf16.h>
#include <cstdint>

#define B_ 2
#define S_ 2048
#define E_ 2048
#define H_ 32
#define KVH_ 8
#define D_ 64

typedef __bf16 bf16;
typedef __bf16 bf16x4 __attribute__((ext_vector_type(4)));
typedef __bf16 bf16x8 __attribute__((ext_vector_type(8)));
typedef float f32x4 __attribute__((ext_vector_type(4)));

// ---------------- cast x (f32) -> bf16 ----------------
__global__ __launch_bounds__(256) void cast_f32_bf16_k(const float* __restrict__ src,
                                                       bf16* __restrict__ dst, int n) {
    int i = (blockIdx.x * 256 + threadIdx.x) * 4;
    if (i < n) {
        f32x4 v = *(const f32x4*)(src + i);
        bf16x4 o;
        o[0] = (bf16)v[0]; o[1] = (bf16)v[1]; o[2] = (bf16)v[2]; o[3] = (bf16)v[3];
        *(bf16x4*)(dst + i) = o;
    }
}

// ---------------- transpose + cast: src f32 [R][C] -> dst bf16 [C][R], R==2048 ----------------
__global__ __launch_bounds__(256) void transpose_cast_k(const float* __restrict__ src,
                                                        bf16* __restrict__ dst, int C) {
    __shared__ float tile[32][33];
    int c0 = blockIdx.x * 32, r0 = blockIdx.y * 32;
    int tx = threadIdx.x, ty = threadIdx.y;  // (32, 8)
#pragma unroll
    for (int i = 0; i < 4; i++)
        tile[ty + 8 * i][tx] = src[(size_t)(r0 + ty + 8 * i) * C + c0 + tx];
    __syncthreads();
#pragma unroll
    for (int i = 0; i < 4; i++)
        dst[(size_t)(c0 + ty + 8 * i) * 2048 + r0 + tx] = (bf16)tile[tx][ty + 8 * i];
}

// ---------------- RoPE cos/sin table: tbl[(s*32+dp)*2] = {cos, sin} ----------------
__global__ __launch_bounds__(256) void rope_table_k(float* __restrict__ tbl) {
    int t = blockIdx.x * 256 + threadIdx.x;  // S_*32 threads
    int dp = t & 31, s = t >> 5;
    float invf = exp2f(-(float)dp * (13.287712379549449f / 32.0f));  // 10000^(-dp/32)
    float ang = (float)s * invf;
    tbl[t * 2] = cosf(ang);
    tbl[t * 2 + 1] = sinf(ang);
}

// ---------------- RoPE apply in-place on bf16 [B][NH][S][64] ----------------
__global__ __launch_bounds__(256) void rope_apply_k(bf16* __restrict__ T,
                                                    const float* __restrict__ tbl, int total) {
    int t = blockIdx.x * 256 + threadIdx.x;
    if (t >= total) return;
    int dp = t & 31;
    int s = (t >> 5) & (S_ - 1);
    int bh = t >> 16;  // 32*2048 = 2^16
    size_t base = ((size_t)bh * S_ + s) * D_ + dp;
    float c = tbl[(s * 32 + dp) * 2], sn = tbl[(s * 32 + dp) * 2 + 1];
    float v1 = (float)T[base], v2 = (float)T[base + 32];
    T[base] = (bf16)(v1 * c - v2 * sn);
    T[base + 32] = (bf16)(v1 * sn + v2 * c);
}

// ---------------- bf16 MFMA GEMM: C[M][N] = A[M][2048] * Bt[N][2048]^T ----------------
// MODE 0: scatter Q [b][h][s][d], K [b][kvh][s][d], V TRANSPOSED [b][kvh][d][s].
// MODE 1: store f32 to Cf [M][2048].
template <int MODE>
__global__ __launch_bounds__(256) void gemm_bf16_k(const bf16* __restrict__ A,
                                                   const bf16* __restrict__ Bt,
                                                   bf16* __restrict__ Q, bf16* __restrict__ Kb,
                                                   bf16* __restrict__ Vb, float* __restrict__ Cf) {
    __shared__ bf16 As[128 * 40];
    __shared__ bf16 Bs[128 * 40];
    const int t = threadIdx.x;
    const int lane = t & 63, w = t >> 6;
    const int wm = w >> 1, wn = w & 1;
    const int g = lane >> 4, l15 = lane & 15;
    const int m0 = blockIdx.y * 128, n0 = blockIdx.x * 128;

    f32x4 acc[4][4];
#pragma unroll
    for (int i = 0; i < 4; i++)
#pragma unroll
        for (int j = 0; j < 4; j++) acc[i][j] = f32x4{0.f, 0.f, 0.f, 0.f};

    const int c0 = t, c1 = t + 256;
    const int ar0 = c0 >> 2, ak0 = (c0 & 3) * 8;
    const int ar1 = c1 >> 2, ak1 = (c1 & 3) * 8;

    for (int k0 = 0; k0 < 2048; k0 += 32) {
        bf16x8 a0 = *(const bf16x8*)(A + (size_t)(m0 + ar0) * 2048 + k0 + ak0);
        bf16x8 a1 = *(const bf16x8*)(A + (size_t)(m0 + ar1) * 2048 + k0 + ak1);
        bf16x8 b0 = *(const bf16x8*)(Bt + (size_t)(n0 + ar0) * 2048 + k0 + ak0);
        bf16x8 b1 = *(const bf16x8*)(Bt + (size_t)(n0 + ar1) * 2048 + k0 + ak1);
        __syncthreads();
        *(bf16x8*)(As + ar0 * 40 + ak0) = a0;
        *(bf16x8*)(As + ar1 * 40 + ak1) = a1;
        *(bf16x8*)(Bs + ar0 * 40 + ak0) = b0;
        *(bf16x8*)(Bs + ar1 * 40 + ak1) = b1;
        __syncthreads();
        bf16x8 af[4], bfr[4];
#pragma unroll
        for (int i = 0; i < 4; i++) {
            af[i] = *(const bf16x8*)(As + (wm * 64 + i * 16 + l15) * 40 + g * 8);
            bfr[i] = *(const bf16x8*)(Bs + (wn * 64 + i * 16 + l15) * 40 + g * 8);
        }
#pragma unroll
        for (int i = 0; i < 4; i++)
#pragma unroll
            for (int j = 0; j < 4; j++)
                acc[i][j] = __builtin_amdgcn_mfma_f32_16x16x32_bf16(af[i], bfr[j], acc[i][j], 0, 0, 0);
    }

#pragma unroll
    for (int i = 0; i < 4; i++) {
        int mB = m0 + wm * 64 + i * 16 + g * 4;
        int b = mB >> 11, s = mB & 2047;
#pragma unroll
        for (int j = 0; j < 4; j++) {
            int n = n0 + wn * 64 + j * 16 + l15;
            f32x4 v = acc[i][j];
            if constexpr (MODE == 0) {
                if (n < 2048) {
                    bf16* dst = Q + (((size_t)b * H_ + (n >> 6)) * S_ + s) * D_ + (n & 63);
#pragma unroll
                    for (int r = 0; r < 4; r++) dst[r * 64] = (bf16)v[r];
                } else if (n < 2560) {
                    bf16* dst = Kb + (((size_t)b * KVH_ + ((n - 2048) >> 6)) * S_ + s) * D_ + (n & 63);
#pragma unroll
                    for (int r = 0; r < 4; r++) dst[r * 64] = (bf16)v[r];
                } else {
                    // V transposed: [b][kvh][d=64][s=2048]
                    int vh = (n - 2560) >> 6, d = n & 63;
                    bf16* dst = Vb + (((size_t)b * KVH_ + vh) * 64 + d) * 2048 + s;
                    bf16x4 o;
#pragma unroll
                    for (int r = 0; r < 4; r++) o[r] = (bf16)v[r];
                    *(bf16x4*)dst = o;
                }
            } else {
#pragma unroll
                for (int r = 0; r < 4; r++) Cf[(size_t)(mB + r) * 2048 + n] = v[r];
            }
        }
    }
}

// ---------------- MFMA flash attention v2: swapped QK^T, in-register softmax ----------------
// Block: 4 waves, 128 q rows of one (b,h); wave w owns q rows qw..qw+31 (2 q-frags of 16 cols).
// S^T = mfma(K_frag, Q_frag): lane (g,l15) holds S[q=qw+mq*16+l15][kv=j0+nf*16+g*4+r].
// O^T = mfma(V^T_frag, P_frag) with shared k-perm (g,e):  kv = kslot*32 + (e>>2)*16 + g*4 + (e&3).
// K LDS row-major [kv][d] (pad 72); V^T LDS [d][kv] (pad 72), staged from pre-transposed global V.
__global__ __launch_bounds__(256) void attn_mfma2_k(const bf16* __restrict__ Q,
                                                    const bf16* __restrict__ Kb,
                                                    const bf16* __restrict__ Vtg,
                                                    bf16* __restrict__ Out) {
    __shared__ bf16 Ks[64 * 72];
    __shared__ bf16 Vts[64 * 72];
    const int t = threadIdx.x;
    const int w = t >> 6, lane = t & 63, g = lane >> 4, l15 = lane & 15;
    const int h = blockIdx.y, b = blockIdx.z;
    const int kvh = h >> 2;
    const int q0 = (15 - blockIdx.x) * 128;  // reversed: biggest blocks dispatched first
    const int qw = q0 + w * 32;

    const bf16* qbase = Q + ((size_t)b * H_ + h) * (size_t)(S_ * D_);
    const bf16* kbase = Kb + ((size_t)b * KVH_ + kvh) * (size_t)(S_ * D_);
    const bf16* vtbase = Vtg + ((size_t)b * KVH_ + kvh) * (size_t)(S_ * D_);

    // Q fragments: B-operand layout, q = col = l15
    bf16x8 qf[2][2];
#pragma unroll
    for (int mq = 0; mq < 2; mq++)
#pragma unroll
        for (int ks = 0; ks < 2; ks++)
            qf[mq][ks] = *(const bf16x8*)(qbase + (size_t)(qw + mq * 16 + l15) * 64 + ks * 32 + g * 8);

    f32x4 accO[4][2];  // [df][mq]: O^T rows d=df*16+g*4+r, col q
    float m_[2] = {-1e30f, -1e30f}, l_[2] = {0.f, 0.f};
#pragma unroll
    for (int df = 0; df < 4; df++)
#pragma unroll
        for (int mq = 0; mq < 2; mq++) accO[df][mq] = f32x4{0.f, 0.f, 0.f, 0.f};

    const float SC = 0.18033688011112042f;  // log2(e)/8

    const int row0 = t >> 3, row1 = row0 + 32;
    const int ch0 = (t & 7) * 8;
    const int nt = q0 / 64 + 2;

    bf16x8 kA, kB, vA, vB;
#define LOADT(J0)                                                          \
    kA = *(const bf16x8*)(kbase + (size_t)((J0) + row0) * 64 + ch0);       \
    kB = *(const bf16x8*)(kbase + (size_t)((J0) + row1) * 64 + ch0);       \
    vA = *(const bf16x8*)(vtbase + (size_t)row0 * 2048 + (J0) + ch0);      \
    vB = *(const bf16x8*)(vtbase + (size_t)row1 * 2048 + (J0) + ch0);

    LOADT(0)
    for (int ti = 0; ti < nt; ti++) {
        const int j0 = ti * 64;
        __syncthreads();  // all waves done reading LDS (prev tile)
        *(bf16x8*)(Ks + row0 * 72 + ch0) = kA;
        *(bf16x8*)(Ks + row1 * 72 + ch0) = kB;
        *(bf16x8*)(Vts + row0 * 72 + ch0) = vA;
        *(bf16x8*)(Vts + row1 * 72 + ch0) = vB;
        __syncthreads();  // staged data visible
        if (ti + 1 < nt) { LOADT(j0 + 64) }  // prefetch hides under compute
        if (j0 > qw + 31) continue;          // fully masked for this wave (barriers still hit)

        // --- QK^T (S^T frags)
        bf16x8 kf[4][2];
#pragma unroll
        for (int nf = 0; nf < 4; nf++)
#pragma unroll
            for (int ks = 0; ks < 2; ks++)
                kf[nf][ks] = *(const bf16x8*)(Ks + (nf * 16 + l15) * 72 + ks * 32 + g * 8);
        f32x4 st[2][4];
#pragma unroll
        for (int mq = 0; mq < 2; mq++)
#pragma unroll
            for (int nf = 0; nf < 4; nf++) {
                st[mq][nf] = f32x4{0.f, 0.f, 0.f, 0.f};
#pragma unroll
                for (int ks = 0; ks < 2; ks++)
                    st[mq][nf] = __builtin_amdgcn_mfma_f32_16x16x32_bf16(kf[nf][ks], qf[mq][ks],
                                                                         st[mq][nf], 0, 0, 0);
            }

        const bool needmask = (j0 + 63 > qw);
        bf16x8 pb[2][2];  // [mq][kslot]
#pragma unroll
        for (int mq = 0; mq < 2; mq++) {
            const int q = qw + mq * 16 + l15;
            float sv[4][4];
#pragma unroll
            for (int nf = 0; nf < 4; nf++)
#pragma unroll
                for (int r = 0; r < 4; r++) {
                    float v = st[mq][nf][r] * SC;
                    if (needmask && (j0 + nf * 16 + g * 4 + r > q)) v = -1e30f;
                    sv[nf][r] = v;
                }
            // in-lane max over 16, then cross-g (2 shuffles)
            float mx = sv[0][0];
#pragma unroll
            for (int nf = 0; nf < 4; nf++)
#pragma unroll
                for (int r = 0; r < 4; r++) mx = fmaxf(mx, sv[nf][r]);
            mx = fmaxf(mx, __shfl_xor(mx, 16));
            mx = fmaxf(mx, __shfl_xor(mx, 32));
            const float mn = fmaxf(m_[mq], mx);
            const float corr = exp2f(m_[mq] - mn);
            m_[mq] = mn;
            float p[4][4];
            float ssum = 0.f;
#pragma unroll
            for (int nf = 0; nf < 4; nf++)
#pragma unroll
                for (int r = 0; r < 4; r++) {
                    p[nf][r] = exp2f(sv[nf][r] - mn);
                    ssum += p[nf][r];
                }
            ssum += __shfl_xor(ssum, 16);
            ssum += __shfl_xor(ssum, 32);
            l_[mq] = l_[mq] * corr + ssum;
#pragma unroll
            for (int df = 0; df < 4; df++)
#pragma unroll
                for (int r = 0; r < 4; r++) accO[df][mq][r] *= corr;
            // pack P to bf16 B-frags with perm e=nf'*4+r  <->  kv=kslot*32+nf'*16+g*4+r
#pragma unroll
            for (int kslot = 0; kslot < 2; kslot++)
#pragma unroll
                for (int nfp = 0; nfp < 2; nfp++)
#pragma unroll
                    for (int r = 0; r < 4; r++)
                        pb[mq][kslot][nfp * 4 + r] = (bf16)p[kslot * 2 + nfp][r];
        }

        // --- PV: O^T += V^T_frag * P_frag (same perm on A side)
#pragma unroll
        for (int df = 0; df < 4; df++) {
            const bf16* vrow = Vts + (df * 16 + l15) * 72;
#pragma unroll
            for (int kslot = 0; kslot < 2; kslot++) {
                bf16x4 lo = *(const bf16x4*)(vrow + kslot * 32 + g * 4);
                bf16x4 hi = *(const bf16x4*)(vrow + kslot * 32 + 16 + g * 4);
                bf16x8 va = __builtin_shufflevector(lo, hi, 0, 1, 2, 3, 4, 5, 6, 7);
#pragma unroll
                for (int mq = 0; mq < 2; mq++)
                    accO[df][mq] = __builtin_amdgcn_mfma_f32_16x16x32_bf16(va, pb[mq][kslot],
                                                                          accO[df][mq], 0, 0, 0);
            }
        }
    }
#undef LOADT

    // --- epilogue: lane holds O^T[d=df*16+g*4+r][q=qw+mq*16+l15]
#pragma unroll
    for (int mq = 0; mq < 2; mq++) {
        const float inv = 1.f / l_[mq];
        const int s = qw + mq * 16 + l15;
        bf16* obase = Out + ((size_t)(b * S_ + s)) * 2048 + h * 64 + g * 4;
#pragma unroll
        for (int df = 0; df < 4; df++) {
            bf16x4 o;
#pragma unroll
            for (int r = 0; r < 4; r++) o[r] = (bf16)(accO[df][mq][r] * inv);
            *(bf16x4*)(obase + df * 16) = o;
        }
    }
}

extern "C" void kernel_launch(void* const* d_in, const int* in_sizes, int n_in,
                              void* d_out, int out_size, void* d_ws, size_t ws_size,
                              hipStream_t stream) {
    const float* x = (const float*)d_in[0];
    const float* Wq = (const float*)d_in[1];
    const float* Wk = (const float*)d_in[2];
    const float* Wv = (const float*)d_in[3];
    const float* Wo = (const float*)d_in[4];
    float* out = (float*)d_out;

    char* ws = (char*)d_ws;
    size_t off = 0;
    auto alloc = [&](size_t bytes) {
        void* p = ws + off;
        off += (bytes + 255) & ~(size_t)255;
        return p;
    };
    bf16* xb = (bf16*)alloc((size_t)4096 * 2048 * 2);
    bf16* WqkvT = (bf16*)alloc((size_t)3072 * 2048 * 2);
    bf16* WoT = (bf16*)alloc((size_t)2048 * 2048 * 2);
    bf16* Qb = (bf16*)alloc((size_t)B_ * H_ * S_ * D_ * 2);
    bf16* Kb = (bf16*)alloc((size_t)B_ * KVH_ * S_ * D_ * 2);
    bf16* Vb = (bf16*)alloc((size_t)B_ * KVH_ * S_ * D_ * 2);  // transposed [b][kvh][d][s]
    float* tbl = (float*)alloc((size_t)S_ * 32 * 2 * sizeof(float));
    bf16* attn = xb;  // alias: xb dead after QKV GEMM

    cast_f32_bf16_k<<<8192, 256, 0, stream>>>(x, xb, 4096 * 2048);
    dim3 tb(32, 8);
    transpose_cast_k<<<dim3(64, 64), tb, 0, stream>>>(Wq, WqkvT, 2048);
    transpose_cast_k<<<dim3(16, 64), tb, 0, stream>>>(Wk, WqkvT + (size_t)2048 * 2048, 512);
    transpose_cast_k<<<dim3(16, 64), tb, 0, stream>>>(Wv, WqkvT + (size_t)2560 * 2048, 512);
    transpose_cast_k<<<dim3(64, 64), tb, 0, stream>>>(Wo, WoT, 2048);
    rope_table_k<<<256, 256, 0, stream>>>(tbl);

    gemm_bf16_k<0><<<dim3(24, 32), 256, 0, stream>>>(xb, WqkvT, Qb, Kb, Vb, nullptr);

    rope_apply_k<<<16384, 256, 0, stream>>>(Qb, tbl, B_ * H_ * S_ * 32);
    rope_apply_k<<<4096, 256, 0, stream>>>(Kb, tbl, B_ * KVH_ * S_ * 32);

    attn_mfma2_k<<<dim3(S_ / 128, H_, B_), 256, 0, stream>>>(Qb, Kb, Vb, attn);

    gemm_bf16_k<1><<<dim3(16, 32), 256, 0, stream>>>(attn, WoT, nullptr, nullptr, nullptr, out);
}

// Round 4
// 310.246 us; speedup vs baseline: 5.5122x; 1.0565x over previous
//
#include <hip/hip_runtime.h>
#include <hip/hip_bf16.h>
#include <cstdint>

#define B_ 2
#define S_ 2048
#define E_ 2048
#define H_ 32
#define KVH_ 8
#define D_ 64

typedef __bf16 bf16;
typedef __bf16 bf16x4 __attribute__((ext_vector_type(4)));
typedef __bf16 bf16x8 __attribute__((ext_vector_type(8)));
typedef float f32x4 __attribute__((ext_vector_type(4)));

// ---------------- cast x (f32) -> bf16 ----------------
__global__ __launch_bounds__(256) void cast_f32_bf16_k(const float* __restrict__ src,
                                                       bf16* __restrict__ dst, int n) {
    int i = (blockIdx.x * 256 + threadIdx.x) * 4;
    if (i < n) {
        f32x4 v = *(const f32x4*)(src + i);
        bf16x4 o;
        o[0] = (bf16)v[0]; o[1] = (bf16)v[1]; o[2] = (bf16)v[2]; o[3] = (bf16)v[3];
        *(bf16x4*)(dst + i) = o;
    }
}

// ---------------- transpose + cast: src f32 [R][C] -> dst bf16 [C][R], R==2048 ----------------
__global__ __launch_bounds__(256) void transpose_cast_k(const float* __restrict__ src,
                                                        bf16* __restrict__ dst, int C) {
    __shared__ float tile[32][33];
    int c0 = blockIdx.x * 32, r0 = blockIdx.y * 32;
    int tx = threadIdx.x, ty = threadIdx.y;  // (32, 8)
#pragma unroll
    for (int i = 0; i < 4; i++)
        tile[ty + 8 * i][tx] = src[(size_t)(r0 + ty + 8 * i) * C + c0 + tx];
    __syncthreads();
#pragma unroll
    for (int i = 0; i < 4; i++)
        dst[(size_t)(c0 + ty + 8 * i) * 2048 + r0 + tx] = (bf16)tile[tx][ty + 8 * i];
}

// ---------------- RoPE cos/sin table: tbl[(s*32+dp)*2] = {cos, sin} ----------------
__global__ __launch_bounds__(256) void rope_table_k(float* __restrict__ tbl) {
    int t = blockIdx.x * 256 + threadIdx.x;  // S_*32 threads
    int dp = t & 31, s = t >> 5;
    float invf = exp2f(-(float)dp * (13.287712379549449f / 32.0f));  // 10000^(-dp/32)
    float ang = (float)s * invf;
    tbl[t * 2] = cosf(ang);
    tbl[t * 2 + 1] = sinf(ang);
}

// ---------------- async global->LDS 16B helper (m97 pattern) ----------------
__device__ __forceinline__ void gload16(const bf16* g, bf16* l) {
    __builtin_amdgcn_global_load_lds((const __attribute__((address_space(1))) uint32_t*)g,
                                     (__attribute__((address_space(3))) uint32_t*)l, 16, 0, 0);
}

// ---------------- bf16 MFMA GEMM: C[M][N] = A[M][2048] * Bt[N][2048]^T ----------------
// global_load_lds staging, linear LDS [128][32], 2-barrier loop (m97 structure).
// MODE 0: fused RoPE on Q/K columns; scatter Q [b][h][s][d], K [b][kvh][s][d],
//         V TRANSPOSED [b][kvh][d][s].
// MODE 1: store f32 to Cf [M][2048].
template <int MODE>
__global__ __launch_bounds__(256) void gemm_bf16_k(const bf16* __restrict__ A,
                                                   const bf16* __restrict__ Bt,
                                                   bf16* __restrict__ Q, bf16* __restrict__ Kb,
                                                   bf16* __restrict__ Vb, float* __restrict__ Cf,
                                                   const float* __restrict__ tbl) {
    __shared__ bf16 As[128 * 32];
    __shared__ bf16 Bs[128 * 32];
    const int t = threadIdx.x;
    const int lane = t & 63, w = t >> 6;
    const int wm = w >> 1, wn = w & 1;
    const int g = lane >> 4, l15 = lane & 15;
    const int m0 = blockIdx.y * 128, n0 = blockIdx.x * 128;

    f32x4 acc[4][4];
#pragma unroll
    for (int i = 0; i < 4; i++)
#pragma unroll
        for (int j = 0; j < 4; j++) acc[i][j] = f32x4{0.f, 0.f, 0.f, 0.f};

    const int srow = t >> 2;         // 0..63
    const int scol = (t & 3) * 8;
    const bf16* ga0 = A + (size_t)(m0 + srow) * 2048 + scol;
    const bf16* ga1 = A + (size_t)(m0 + 64 + srow) * 2048 + scol;
    const bf16* gb0 = Bt + (size_t)(n0 + srow) * 2048 + scol;
    const bf16* gb1 = Bt + (size_t)(n0 + 64 + srow) * 2048 + scol;
    bf16* la = As + w * 512;  // wave-uniform LDS dest; HW adds lane*16B
    bf16* lb = Bs + w * 512;

    for (int k0 = 0; k0 < 2048; k0 += 32) {
        __syncthreads();  // everyone done reading LDS of prev step
        gload16(ga0 + k0, la);
        gload16(ga1 + k0, la + 2048);
        gload16(gb0 + k0, lb);
        gload16(gb1 + k0, lb + 2048);
        __syncthreads();  // vmcnt(0) drain + visibility
        bf16x8 af[4], bfr[4];
#pragma unroll
        for (int i = 0; i < 4; i++) {
            af[i] = *(const bf16x8*)(As + (wm * 64 + i * 16 + l15) * 32 + g * 8);
            bfr[i] = *(const bf16x8*)(Bs + (wn * 64 + i * 16 + l15) * 32 + g * 8);
        }
#pragma unroll
        for (int i = 0; i < 4; i++)
#pragma unroll
            for (int j = 0; j < 4; j++)
                acc[i][j] = __builtin_amdgcn_mfma_f32_16x16x32_bf16(af[i], bfr[j], acc[i][j], 0, 0, 0);
    }

    const int nbase = n0 + wn * 64;  // 64-aligned => whole j-span is one head/region
#pragma unroll
    for (int i = 0; i < 4; i++) {
        int mB = m0 + wm * 64 + i * 16 + g * 4;
        int b = mB >> 11, s = mB & 2047;
        if constexpr (MODE == 0) {
            if (nbase < 2560) {
                // fused RoPE on columns: pairs (j, j+2) == dims (d, d+32), d = j*16+l15
#pragma unroll
                for (int jh = 0; jh < 2; jh++) {
                    int dp = jh * 16 + l15;
#pragma unroll
                    for (int r = 0; r < 4; r++) {
                        const float* cs = tbl + ((size_t)(s + r) * 32 + dp) * 2;
                        float cv = cs[0], sv = cs[1];
                        float lo = acc[i][jh][r], hi = acc[i][jh + 2][r];
                        acc[i][jh][r] = lo * cv - hi * sv;
                        acc[i][jh + 2][r] = lo * sv + hi * cv;
                    }
                }
            }
        }
#pragma unroll
        for (int j = 0; j < 4; j++) {
            int n = nbase + j * 16 + l15;
            f32x4 v = acc[i][j];
            if constexpr (MODE == 0) {
                if (n < 2048) {
                    bf16* dst = Q + (((size_t)b * H_ + (n >> 6)) * S_ + s) * D_ + (n & 63);
#pragma unroll
                    for (int r = 0; r < 4; r++) dst[r * 64] = (bf16)v[r];
                } else if (n < 2560) {
                    bf16* dst = Kb + (((size_t)b * KVH_ + ((n - 2048) >> 6)) * S_ + s) * D_ + (n & 63);
#pragma unroll
                    for (int r = 0; r < 4; r++) dst[r * 64] = (bf16)v[r];
                } else {
                    // V transposed: [b][kvh][d=64][s=2048]
                    int vh = (n - 2560) >> 6, d = n & 63;
                    bf16* dst = Vb + (((size_t)b * KVH_ + vh) * 64 + d) * 2048 + s;
                    bf16x4 o;
#pragma unroll
                    for (int r = 0; r < 4; r++) o[r] = (bf16)v[r];
                    *(bf16x4*)dst = o;
                }
            } else {
#pragma unroll
                for (int r = 0; r < 4; r++) Cf[(size_t)(mB + r) * 2048 + n] = v[r];
            }
        }
    }
}

// ---------------- MFMA flash attention v3: causal-pair-balanced ----------------
// Block = 4 waves; pair id c: handles 64-row chunk c AND chunk 31-c of one (b,h).
// Wave w owns 16-row frag qw0 = 64c + 16w (mq=0) and qw1 = 64(31-c) + 16w (mq=1).
// Every block: 33 frag-tile units (perfectly balanced compute); nt = 32-c staging iters.
// S^T = mfma(K_frag, Q_frag): lane (g,l15) holds S[q=qw+l15][kv=j0+nf*16+g*4+r].
// O^T = mfma(V^T_frag, P_frag), shared k-perm on both operands (exact).
__global__ __launch_bounds__(256) void attn_mfma3_k(const bf16* __restrict__ Q,
                                                    const bf16* __restrict__ Kb,
                                                    const bf16* __restrict__ Vtg,
                                                    bf16* __restrict__ Out) {
    __shared__ bf16 Ks[64 * 72];
    __shared__ bf16 Vts[64 * 72];
    const int t = threadIdx.x;
    const int w = t >> 6, lane = t & 63, g = lane >> 4, l15 = lane & 15;
    const int h = blockIdx.y, b = blockIdx.z;
    const int kvh = h >> 2;
    const int c = blockIdx.x;  // pair id 0..15
    const int qw[2] = {c * 64 + w * 16, (31 - c) * 64 + w * 16};
    const int nt = 32 - c;

    const bf16* qbase = Q + ((size_t)b * H_ + h) * (size_t)(S_ * D_);
    const bf16* kbase = Kb + ((size_t)b * KVH_ + kvh) * (size_t)(S_ * D_);
    const bf16* vtbase = Vtg + ((size_t)b * KVH_ + kvh) * (size_t)(S_ * D_);

    // Q fragments (B-operand layout, q = col = l15)
    bf16x8 qf[2][2];
#pragma unroll
    for (int mq = 0; mq < 2; mq++)
#pragma unroll
        for (int ks = 0; ks < 2; ks++)
            qf[mq][ks] = *(const bf16x8*)(qbase + (size_t)(qw[mq] + l15) * 64 + ks * 32 + g * 8);

    f32x4 accO[4][2];  // [df][mq]: O^T rows d=df*16+g*4+r, col q=l15
    float m_[2] = {-1e30f, -1e30f}, l_[2] = {0.f, 0.f};
#pragma unroll
    for (int df = 0; df < 4; df++)
#pragma unroll
        for (int mq = 0; mq < 2; mq++) accO[df][mq] = f32x4{0.f, 0.f, 0.f, 0.f};

    const float SC = 0.18033688011112042f;  // log2(e)/8

    const int row0 = t >> 3, row1 = row0 + 32;
    const int ch0 = (t & 7) * 8;

    bf16x8 kA, kB, vA, vB;
#define LOADT(J0)                                                          \
    kA = *(const bf16x8*)(kbase + (size_t)((J0) + row0) * 64 + ch0);       \
    kB = *(const bf16x8*)(kbase + (size_t)((J0) + row1) * 64 + ch0);       \
    vA = *(const bf16x8*)(vtbase + (size_t)row0 * 2048 + (J0) + ch0);      \
    vB = *(const bf16x8*)(vtbase + (size_t)row1 * 2048 + (J0) + ch0);

    LOADT(0)
    for (int ti = 0; ti < nt; ti++) {
        const int j0 = ti * 64;
        __syncthreads();  // all waves done reading LDS (prev tile)
        *(bf16x8*)(Ks + row0 * 72 + ch0) = kA;
        *(bf16x8*)(Ks + row1 * 72 + ch0) = kB;
        *(bf16x8*)(Vts + row0 * 72 + ch0) = vA;
        *(bf16x8*)(Vts + row1 * 72 + ch0) = vB;
        __syncthreads();  // staged data visible
        if (ti + 1 < nt) { LOADT(j0 + 64) }  // prefetch hides under compute
        const bool act0 = (ti <= c);         // low frag still active?

        // --- K frags (shared by both q-frags)
        bf16x8 kf[4][2];
#pragma unroll
        for (int nf = 0; nf < 4; nf++)
#pragma unroll
            for (int ks = 0; ks < 2; ks++)
                kf[nf][ks] = *(const bf16x8*)(Ks + (nf * 16 + l15) * 72 + ks * 32 + g * 8);

        bf16x8 pb[2][2];  // [mq][kslot]
#pragma unroll
        for (int mq = 0; mq < 2; mq++) {
            if (mq == 0 && !act0) continue;
            f32x4 st[4];
#pragma unroll
            for (int nf = 0; nf < 4; nf++) {
                st[nf] = f32x4{0.f, 0.f, 0.f, 0.f};
#pragma unroll
                for (int ks = 0; ks < 2; ks++)
                    st[nf] = __builtin_amdgcn_mfma_f32_16x16x32_bf16(kf[nf][ks], qf[mq][ks],
                                                                     st[nf], 0, 0, 0);
            }
            const int q = qw[mq] + l15;
            const bool needmask = (j0 + 63 > qw[mq]);
            float sv[4][4];
#pragma unroll
            for (int nf = 0; nf < 4; nf++)
#pragma unroll
                for (int r = 0; r < 4; r++) {
                    float v = st[nf][r] * SC;
                    if (needmask && (j0 + nf * 16 + g * 4 + r > q)) v = -1e30f;
                    sv[nf][r] = v;
                }
            float mx = sv[0][0];
#pragma unroll
            for (int nf = 0; nf < 4; nf++)
#pragma unroll
                for (int r = 0; r < 4; r++) mx = fmaxf(mx, sv[nf][r]);
            mx = fmaxf(mx, __shfl_xor(mx, 16));
            mx = fmaxf(mx, __shfl_xor(mx, 32));
            const float mn = fmaxf(m_[mq], mx);
            const float corr = exp2f(m_[mq] - mn);
            m_[mq] = mn;
            float p[4][4];
            float ssum = 0.f;
#pragma unroll
            for (int nf = 0; nf < 4; nf++)
#pragma unroll
                for (int r = 0; r < 4; r++) {
                    p[nf][r] = exp2f(sv[nf][r] - mn);
                    ssum += p[nf][r];
                }
            ssum += __shfl_xor(ssum, 16);
            ssum += __shfl_xor(ssum, 32);
            l_[mq] = l_[mq] * corr + ssum;
#pragma unroll
            for (int df = 0; df < 4; df++)
#pragma unroll
                for (int r = 0; r < 4; r++) accO[df][mq][r] *= corr;
            // pack P to bf16 B-frags: e=nf'*4+r  <->  kv=kslot*32+nf'*16+g*4+r
#pragma unroll
            for (int kslot = 0; kslot < 2; kslot++)
#pragma unroll
                for (int nfp = 0; nfp < 2; nfp++)
#pragma unroll
                    for (int r = 0; r < 4; r++)
                        pb[mq][kslot][nfp * 4 + r] = (bf16)p[kslot * 2 + nfp][r];
        }

        // --- PV: O^T += V^T_frag * P_frag (same k-perm on A side)
#pragma unroll
        for (int df = 0; df < 4; df++) {
            const bf16* vrow = Vts + (df * 16 + l15) * 72;
#pragma unroll
            for (int kslot = 0; kslot < 2; kslot++) {
                bf16x4 lo = *(const bf16x4*)(vrow + kslot * 32 + g * 4);
                bf16x4 hi = *(const bf16x4*)(vrow + kslot * 32 + 16 + g * 4);
                bf16x8 va = __builtin_shufflevector(lo, hi, 0, 1, 2, 3, 4, 5, 6, 7);
                accO[df][1] = __builtin_amdgcn_mfma_f32_16x16x32_bf16(va, pb[1][kslot],
                                                                     accO[df][1], 0, 0, 0);
                if (act0)
                    accO[df][0] = __builtin_amdgcn_mfma_f32_16x16x32_bf16(va, pb[0][kslot],
                                                                         accO[df][0], 0, 0, 0);
            }
        }
    }
#undef LOADT

    // --- epilogue: lane holds O^T[d=df*16+g*4+r][q=qw[mq]+l15]
#pragma unroll
    for (int mq = 0; mq < 2; mq++) {
        const float inv = 1.f / l_[mq];
        const int s = qw[mq] + l15;
        bf16* obase = Out + ((size_t)(b * S_ + s)) * 2048 + h * 64 + g * 4;
#pragma unroll
        for (int df = 0; df < 4; df++) {
            bf16x4 o;
#pragma unroll
            for (int r = 0; r < 4; r++) o[r] = (bf16)(accO[df][mq][r] * inv);
            *(bf16x4*)(obase + df * 16) = o;
        }
    }
}

extern "C" void kernel_launch(void* const* d_in, const int* in_sizes, int n_in,
                              void* d_out, int out_size, void* d_ws, size_t ws_size,
                              hipStream_t stream) {
    const float* x = (const float*)d_in[0];
    const float* Wq = (const float*)d_in[1];
    const float* Wk = (const float*)d_in[2];
    const float* Wv = (const float*)d_in[3];
    const float* Wo = (const float*)d_in[4];
    float* out = (float*)d_out;

    char* ws = (char*)d_ws;
    size_t off = 0;
    auto alloc = [&](size_t bytes) {
        void* p = ws + off;
        off += (bytes + 255) & ~(size_t)255;
        return p;
    };
    bf16* xb = (bf16*)alloc((size_t)4096 * 2048 * 2);
    bf16* WqkvT = (bf16*)alloc((size_t)3072 * 2048 * 2);
    bf16* WoT = (bf16*)alloc((size_t)2048 * 2048 * 2);
    bf16* Qb = (bf16*)alloc((size_t)B_ * H_ * S_ * D_ * 2);
    bf16* Kb = (bf16*)alloc((size_t)B_ * KVH_ * S_ * D_ * 2);
    bf16* Vb = (bf16*)alloc((size_t)B_ * KVH_ * S_ * D_ * 2);  // transposed [b][kvh][d][s]
    float* tbl = (float*)alloc((size_t)S_ * 32 * 2 * sizeof(float));
    bf16* attn = xb;  // alias: xb dead after QKV GEMM

    cast_f32_bf16_k<<<8192, 256, 0, stream>>>(x, xb, 4096 * 2048);
    dim3 tb(32, 8);
    transpose_cast_k<<<dim3(64, 64), tb, 0, stream>>>(Wq, WqkvT, 2048);
    transpose_cast_k<<<dim3(16, 64), tb, 0, stream>>>(Wk, WqkvT + (size_t)2048 * 2048, 512);
    transpose_cast_k<<<dim3(16, 64), tb, 0, stream>>>(Wv, WqkvT + (size_t)2560 * 2048, 512);
    transpose_cast_k<<<dim3(64, 64), tb, 0, stream>>>(Wo, WoT, 2048);
    rope_table_k<<<256, 256, 0, stream>>>(tbl);

    // QKV GEMM with fused RoPE (needs tbl)
    gemm_bf16_k<0><<<dim3(24, 32), 256, 0, stream>>>(xb, WqkvT, Qb, Kb, Vb, nullptr, tbl);

    attn_mfma3_k<<<dim3(16, H_, B_), 256, 0, stream>>>(Qb, Kb, Vb, attn);

    gemm_bf16_k<1><<<dim3(16, 32), 256, 0, stream>>>(attn, WoT, nullptr, nullptr, nullptr, out, nullptr);
}

// Round 5
// 258.912 us; speedup vs baseline: 6.6051x; 1.1983x over previous
//
#include <hip/hip_runtime.h>
#include <hip/hip_bf16.h>
#include <cstdint>

#define B_ 2
#define S_ 2048
#define E_ 2048
#define H_ 32
#define KVH_ 8
#define D_ 64

typedef __bf16 bf16;
typedef __bf16 bf16x4 __attribute__((ext_vector_type(4)));
typedef __bf16 bf16x8 __attribute__((ext_vector_type(8)));
typedef float f32x4 __attribute__((ext_vector_type(4)));

// ---------------- cast x (f32) -> bf16 ----------------
__global__ __launch_bounds__(256) void cast_f32_bf16_k(const float* __restrict__ src,
                                                       bf16* __restrict__ dst, int n) {
    int i = (blockIdx.x * 256 + threadIdx.x) * 4;
    if (i < n) {
        f32x4 v = *(const f32x4*)(src + i);
        bf16x4 o;
        o[0] = (bf16)v[0]; o[1] = (bf16)v[1]; o[2] = (bf16)v[2]; o[3] = (bf16)v[3];
        *(bf16x4*)(dst + i) = o;
    }
}

// ---------------- transpose + cast: src f32 [R][C] -> dst bf16 [C][R], R==2048 ----------------
__global__ __launch_bounds__(256) void transpose_cast_k(const float* __restrict__ src,
                                                        bf16* __restrict__ dst, int C) {
    __shared__ float tile[32][33];
    int c0 = blockIdx.x * 32, r0 = blockIdx.y * 32;
    int tx = threadIdx.x, ty = threadIdx.y;  // (32, 8)
#pragma unroll
    for (int i = 0; i < 4; i++)
        tile[ty + 8 * i][tx] = src[(size_t)(r0 + ty + 8 * i) * C + c0 + tx];
    __syncthreads();
#pragma unroll
    for (int i = 0; i < 4; i++)
        dst[(size_t)(c0 + ty + 8 * i) * 2048 + r0 + tx] = (bf16)tile[tx][ty + 8 * i];
}

// ---------------- RoPE cos/sin table: tbl[(s*32+dp)*2] = {cos, sin} ----------------
__global__ __launch_bounds__(256) void rope_table_k(float* __restrict__ tbl) {
    int t = blockIdx.x * 256 + threadIdx.x;  // S_*32 threads
    int dp = t & 31, s = t >> 5;
    float invf = exp2f(-(float)dp * (13.287712379549449f / 32.0f));  // 10000^(-dp/32)
    float ang = (float)s * invf;
    tbl[t * 2] = cosf(ang);
    tbl[t * 2 + 1] = sinf(ang);
}

// ---------------- async global->LDS 16B helper (m97 pattern) ----------------
__device__ __forceinline__ void gload16(const bf16* g, bf16* l) {
    __builtin_amdgcn_global_load_lds((const __attribute__((address_space(1))) uint32_t*)g,
                                     (__attribute__((address_space(3))) uint32_t*)l, 16, 0, 0);
}

// ---------------- bf16 MFMA GEMM: C[M][N] = A[M][2048] * Bt[N][2048]^T ----------------
// global_load_lds staging, linear LDS [128][32], 2-barrier loop (m97 structure), XCD swizzle.
// MODE 0: fused RoPE on Q/K columns; scatter Q [b][h][s][d], K [b][kvh][s][d],
//         V TRANSPOSED [b][kvh][d][s].
// MODE 1: store f32 to Cf [M][2048].
template <int MODE>
__global__ __launch_bounds__(256) void gemm_bf16_k(const bf16* __restrict__ A,
                                                   const bf16* __restrict__ Bt,
                                                   bf16* __restrict__ Q, bf16* __restrict__ Kb,
                                                   bf16* __restrict__ Vb, float* __restrict__ Cf,
                                                   const float* __restrict__ tbl) {
    __shared__ bf16 As[128 * 32];
    __shared__ bf16 Bs[128 * 32];
    const int t = threadIdx.x;
    const int lane = t & 63, w = t >> 6;
    const int wm = w >> 1, wn = w & 1;
    const int g = lane >> 4, l15 = lane & 15;
    // XCD-aware swizzle (nwg % 8 == 0 for both call sites)
    const int flat = blockIdx.x + gridDim.x * blockIdx.y;
    const int cpx = (gridDim.x * gridDim.y) >> 3;
    const int swz = (flat & 7) * cpx + (flat >> 3);
    const int m0 = (swz / gridDim.x) * 128, n0 = (swz % gridDim.x) * 128;

    f32x4 acc[4][4];
#pragma unroll
    for (int i = 0; i < 4; i++)
#pragma unroll
        for (int j = 0; j < 4; j++) acc[i][j] = f32x4{0.f, 0.f, 0.f, 0.f};

    const int srow = t >> 2;         // 0..63
    const int scol = (t & 3) * 8;
    const bf16* ga0 = A + (size_t)(m0 + srow) * 2048 + scol;
    const bf16* ga1 = A + (size_t)(m0 + 64 + srow) * 2048 + scol;
    const bf16* gb0 = Bt + (size_t)(n0 + srow) * 2048 + scol;
    const bf16* gb1 = Bt + (size_t)(n0 + 64 + srow) * 2048 + scol;
    bf16* la = As + w * 512;  // wave-uniform LDS dest; HW adds lane*16B
    bf16* lb = Bs + w * 512;

    for (int k0 = 0; k0 < 2048; k0 += 32) {
        __syncthreads();  // everyone done reading LDS of prev step
        gload16(ga0 + k0, la);
        gload16(ga1 + k0, la + 2048);
        gload16(gb0 + k0, lb);
        gload16(gb1 + k0, lb + 2048);
        __syncthreads();  // vmcnt(0) drain + visibility
        bf16x8 af[4], bfr[4];
#pragma unroll
        for (int i = 0; i < 4; i++) {
            af[i] = *(const bf16x8*)(As + (wm * 64 + i * 16 + l15) * 32 + g * 8);
            bfr[i] = *(const bf16x8*)(Bs + (wn * 64 + i * 16 + l15) * 32 + g * 8);
        }
#pragma unroll
        for (int i = 0; i < 4; i++)
#pragma unroll
            for (int j = 0; j < 4; j++)
                acc[i][j] = __builtin_amdgcn_mfma_f32_16x16x32_bf16(af[i], bfr[j], acc[i][j], 0, 0, 0);
    }

    const int nbase = n0 + wn * 64;  // 64-aligned => whole j-span is one head/region
#pragma unroll
    for (int i = 0; i < 4; i++) {
        int mB = m0 + wm * 64 + i * 16 + g * 4;
        int b = mB >> 11, s = mB & 2047;
        if constexpr (MODE == 0) {
            if (nbase < 2560) {
                // fused RoPE on columns: pairs (j, j+2) == dims (d, d+32), d = j*16+l15
#pragma unroll
                for (int jh = 0; jh < 2; jh++) {
                    int dp = jh * 16 + l15;
#pragma unroll
                    for (int r = 0; r < 4; r++) {
                        const float* cs = tbl + ((size_t)(s + r) * 32 + dp) * 2;
                        float cv = cs[0], sv = cs[1];
                        float lo = acc[i][jh][r], hi = acc[i][jh + 2][r];
                        acc[i][jh][r] = lo * cv - hi * sv;
                        acc[i][jh + 2][r] = lo * sv + hi * cv;
                    }
                }
            }
        }
#pragma unroll
        for (int j = 0; j < 4; j++) {
            int n = nbase + j * 16 + l15;
            f32x4 v = acc[i][j];
            if constexpr (MODE == 0) {
                if (n < 2048) {
                    bf16* dst = Q + (((size_t)b * H_ + (n >> 6)) * S_ + s) * D_ + (n & 63);
#pragma unroll
                    for (int r = 0; r < 4; r++) dst[r * 64] = (bf16)v[r];
                } else if (n < 2560) {
                    bf16* dst = Kb + (((size_t)b * KVH_ + ((n - 2048) >> 6)) * S_ + s) * D_ + (n & 63);
#pragma unroll
                    for (int r = 0; r < 4; r++) dst[r * 64] = (bf16)v[r];
                } else {
                    // V transposed: [b][kvh][d=64][s=2048]
                    int vh = (n - 2560) >> 6, d = n & 63;
                    bf16* dst = Vb + (((size_t)b * KVH_ + vh) * 64 + d) * 2048 + s;
                    bf16x4 o;
#pragma unroll
                    for (int r = 0; r < 4; r++) o[r] = (bf16)v[r];
                    *(bf16x4*)dst = o;
                }
            } else {
#pragma unroll
                for (int r = 0; r < 4; r++) Cf[(size_t)(mB + r) * 2048 + n] = v[r];
            }
        }
    }
}

// ---------------- MFMA flash attention v4: GQA 4-head blocks, 8 waves ----------------
// Grid (16, KVH, B) = 256 blocks = 1/CU, all resident. Block = 512 thr = 8 waves.
// Wave w: head hh=w>>1 (of this kvh group), half u=w&1. Covers chunks C0=c and C1=31-c:
// rows CX*64 + u*32 + f*16 + l15, f=0,1. K/V staged ONCE per block, shared by 4 heads.
// S^T = mfma(K_frag, Q_frag*SC): lane (g,l15) holds S[q][kv=j0+nf*16+g*4+r].
// O^T = mfma(V^T_frag, P_frag), shared k-perm on both operands (exact).
__global__ __launch_bounds__(512, 2) void attn_mfma4_k(const bf16* __restrict__ Q,
                                                       const bf16* __restrict__ Kb,
                                                       const bf16* __restrict__ Vtg,
                                                       bf16* __restrict__ Out) {
    __shared__ bf16 Ks[64 * 72];
    __shared__ bf16 Vts[64 * 72];
    const int t = threadIdx.x;
    const int w = t >> 6, lane = t & 63, g = lane >> 4, l15 = lane & 15;
    const int hh = w >> 1, u = w & 1;
    const int kvh = blockIdx.y, b = blockIdx.z;
    const int h = kvh * 4 + hh;
    const int c = blockIdx.x;  // pair id 0..15; chunks c and 31-c
    const int qb[2] = {c * 64 + u * 32, (31 - c) * 64 + u * 32};
    const int nt = 32 - c;

    const bf16* qbase = Q + ((size_t)b * H_ + h) * (size_t)(S_ * D_);
    const bf16* kbase = Kb + ((size_t)b * KVH_ + kvh) * (size_t)(S_ * D_);
    const bf16* vtbase = Vtg + ((size_t)b * KVH_ + kvh) * (size_t)(S_ * D_);

    const float SC = 0.18033688011112042f;  // log2(e)/8, folded into Q frags

    // Q fragments (B-operand layout, q = col = l15), pre-scaled by SC
    bf16x8 qf[2][2][2];  // [cidx][f][ks]
#pragma unroll
    for (int cidx = 0; cidx < 2; cidx++)
#pragma unroll
        for (int f = 0; f < 2; f++)
#pragma unroll
            for (int ks = 0; ks < 2; ks++) {
                bf16x8 raw = *(const bf16x8*)(qbase + (size_t)(qb[cidx] + f * 16 + l15) * 64 +
                                              ks * 32 + g * 8);
                bf16x8 sc8;
#pragma unroll
                for (int e = 0; e < 8; e++) sc8[e] = (bf16)((float)raw[e] * SC);
                qf[cidx][f][ks] = sc8;
            }

    f32x4 accO[4][2][2];  // [df][cidx][f]: O^T rows d=df*16+g*4+r, col q=l15
    float m_[2][2], l_[2][2];
#pragma unroll
    for (int cidx = 0; cidx < 2; cidx++)
#pragma unroll
        for (int f = 0; f < 2; f++) {
            m_[cidx][f] = -1e30f;
            l_[cidx][f] = 0.f;
#pragma unroll
            for (int df = 0; df < 4; df++) accO[df][cidx][f] = f32x4{0.f, 0.f, 0.f, 0.f};
        }

    const int row0 = t >> 3;          // 0..63 (512 threads cover the whole tile)
    const int ch0 = (t & 7) * 8;

    bf16x8 kA, vA;
#define LOADT(J0)                                                     \
    kA = *(const bf16x8*)(kbase + (size_t)((J0) + row0) * 64 + ch0);  \
    vA = *(const bf16x8*)(vtbase + (size_t)row0 * 2048 + (J0) + ch0);

    LOADT(0)
    for (int ti = 0; ti < nt; ti++) {
        const int j0 = ti * 64;
        __syncthreads();  // all waves done reading LDS (prev tile)
        *(bf16x8*)(Ks + row0 * 72 + ch0) = kA;
        *(bf16x8*)(Vts + row0 * 72 + ch0) = vA;
        __syncthreads();  // staged data visible
        if (ti + 1 < nt) { LOADT(j0 + 64) }  // prefetch hides under compute

        // --- K frags (shared by all 4 units of this wave)
        bf16x8 kf[4][2];
#pragma unroll
        for (int nf = 0; nf < 4; nf++)
#pragma unroll
            for (int ks = 0; ks < 2; ks++)
                kf[nf][ks] = *(const bf16x8*)(Ks + (nf * 16 + l15) * 72 + ks * 32 + g * 8);

#pragma unroll
        for (int cidx = 0; cidx < 2; cidx++) {
            if (cidx == 0 && ti > c) continue;  // low chunk fully done
            bf16x8 pb[2][2];  // [f][kslot]
#pragma unroll
            for (int f = 0; f < 2; f++) {
                f32x4 st[4];
#pragma unroll
                for (int nf = 0; nf < 4; nf++) {
                    st[nf] = f32x4{0.f, 0.f, 0.f, 0.f};
#pragma unroll
                    for (int ks = 0; ks < 2; ks++)
                        st[nf] = __builtin_amdgcn_mfma_f32_16x16x32_bf16(kf[nf][ks],
                                                                         qf[cidx][f][ks],
                                                                         st[nf], 0, 0, 0);
                }
                const int qrow0 = qb[cidx] + f * 16;
                const int q = qrow0 + l15;
                float sv[4][4];
                if (j0 + 63 > qrow0) {  // diagonal tile: mask
#pragma unroll
                    for (int nf = 0; nf < 4; nf++)
#pragma unroll
                        for (int r = 0; r < 4; r++)
                            sv[nf][r] = (j0 + nf * 16 + g * 4 + r > q) ? -1e30f : st[nf][r];
                } else {
#pragma unroll
                    for (int nf = 0; nf < 4; nf++)
#pragma unroll
                        for (int r = 0; r < 4; r++) sv[nf][r] = st[nf][r];
                }
                // row max: tree in-lane, then cross-g
                float m01, m23, mx;
                m01 = fmaxf(fmaxf(sv[0][0], sv[0][1]), fmaxf(sv[0][2], sv[0][3]));
                m23 = fmaxf(fmaxf(sv[1][0], sv[1][1]), fmaxf(sv[1][2], sv[1][3]));
                mx = fmaxf(m01, m23);
                m01 = fmaxf(fmaxf(sv[2][0], sv[2][1]), fmaxf(sv[2][2], sv[2][3]));
                m23 = fmaxf(fmaxf(sv[3][0], sv[3][1]), fmaxf(sv[3][2], sv[3][3]));
                mx = fmaxf(mx, fmaxf(m01, m23));
                mx = fmaxf(mx, __shfl_xor(mx, 16));
                mx = fmaxf(mx, __shfl_xor(mx, 32));
                // defer-max (T13): only rescale when max grew by > 8 (log2 domain)
                if (!__all(mx - m_[cidx][f] <= 8.f)) {
                    const float mn = fmaxf(m_[cidx][f], mx);
                    const float corr = exp2f(m_[cidx][f] - mn);
                    m_[cidx][f] = mn;
                    l_[cidx][f] *= corr;
#pragma unroll
                    for (int df = 0; df < 4; df++)
#pragma unroll
                        for (int r = 0; r < 4; r++) accO[df][cidx][f][r] *= corr;
                }
                const float mcur = m_[cidx][f];
                float p[4][4];
                float ssum = 0.f;
#pragma unroll
                for (int nf = 0; nf < 4; nf++)
#pragma unroll
                    for (int r = 0; r < 4; r++) {
                        p[nf][r] = exp2f(sv[nf][r] - mcur);
                        ssum += p[nf][r];
                    }
                ssum += __shfl_xor(ssum, 16);
                ssum += __shfl_xor(ssum, 32);
                l_[cidx][f] += ssum;
                // pack P to bf16 B-frags: e=nfp*4+r  <->  kv=kslot*32+nfp*16+g*4+r
#pragma unroll
                for (int kslot = 0; kslot < 2; kslot++)
#pragma unroll
                    for (int nfp = 0; nfp < 2; nfp++)
#pragma unroll
                        for (int r = 0; r < 4; r++)
                            pb[f][kslot][nfp * 4 + r] = (bf16)p[kslot * 2 + nfp][r];
            }

            // --- PV for this chunk: O^T += V^T_frag * P_frag (same k-perm on A side)
#pragma unroll
            for (int df = 0; df < 4; df++) {
                const bf16* vrow = Vts + (df * 16 + l15) * 72;
#pragma unroll
                for (int kslot = 0; kslot < 2; kslot++) {
                    bf16x4 lo = *(const bf16x4*)(vrow + kslot * 32 + g * 4);
                    bf16x4 hi = *(const bf16x4*)(vrow + kslot * 32 + 16 + g * 4);
                    bf16x8 va = __builtin_shufflevector(lo, hi, 0, 1, 2, 3, 4, 5, 6, 7);
#pragma unroll
                    for (int f = 0; f < 2; f++)
                        accO[df][cidx][f] = __builtin_amdgcn_mfma_f32_16x16x32_bf16(
                            va, pb[f][kslot], accO[df][cidx][f], 0, 0, 0);
                }
            }
        }
    }
#undef LOADT

    // --- epilogue: lane holds O^T[d=df*16+g*4+r][q=qb[cidx]+f*16+l15]
#pragma unroll
    for (int cidx = 0; cidx < 2; cidx++)
#pragma unroll
        for (int f = 0; f < 2; f++) {
            const float inv = 1.f / l_[cidx][f];
            const int s = qb[cidx] + f * 16 + l15;
            bf16* obase = Out + ((size_t)(b * S_ + s)) * 2048 + h * 64 + g * 4;
#pragma unroll
            for (int df = 0; df < 4; df++) {
                bf16x4 o;
#pragma unroll
                for (int r = 0; r < 4; r++) o[r] = (bf16)(accO[df][cidx][f][r] * inv);
                *(bf16x4*)(obase + df * 16) = o;
            }
        }
}

extern "C" void kernel_launch(void* const* d_in, const int* in_sizes, int n_in,
                              void* d_out, int out_size, void* d_ws, size_t ws_size,
                              hipStream_t stream) {
    const float* x = (const float*)d_in[0];
    const float* Wq = (const float*)d_in[1];
    const float* Wk = (const float*)d_in[2];
    const float* Wv = (const float*)d_in[3];
    const float* Wo = (const float*)d_in[4];
    float* out = (float*)d_out;

    char* ws = (char*)d_ws;
    size_t off = 0;
    auto alloc = [&](size_t bytes) {
        void* p = ws + off;
        off += (bytes + 255) & ~(size_t)255;
        return p;
    };
    bf16* xb = (bf16*)alloc((size_t)4096 * 2048 * 2);
    bf16* WqkvT = (bf16*)alloc((size_t)3072 * 2048 * 2);
    bf16* WoT = (bf16*)alloc((size_t)2048 * 2048 * 2);
    bf16* Qb = (bf16*)alloc((size_t)B_ * H_ * S_ * D_ * 2);
    bf16* Kb = (bf16*)alloc((size_t)B_ * KVH_ * S_ * D_ * 2);
    bf16* Vb = (bf16*)alloc((size_t)B_ * KVH_ * S_ * D_ * 2);  // transposed [b][kvh][d][s]
    float* tbl = (float*)alloc((size_t)S_ * 32 * 2 * sizeof(float));
    bf16* attn = xb;  // alias: xb dead after QKV GEMM

    cast_f32_bf16_k<<<8192, 256, 0, stream>>>(x, xb, 4096 * 2048);
    dim3 tb(32, 8);
    transpose_cast_k<<<dim3(64, 64), tb, 0, stream>>>(Wq, WqkvT, 2048);
    transpose_cast_k<<<dim3(16, 64), tb, 0, stream>>>(Wk, WqkvT + (size_t)2048 * 2048, 512);
    transpose_cast_k<<<dim3(16, 64), tb, 0, stream>>>(Wv, WqkvT + (size_t)2560 * 2048, 512);
    transpose_cast_k<<<dim3(64, 64), tb, 0, stream>>>(Wo, WoT, 2048);
    rope_table_k<<<256, 256, 0, stream>>>(tbl);

    // QKV GEMM with fused RoPE (needs tbl)
    gemm_bf16_k<0><<<dim3(24, 32), 256, 0, stream>>>(xb, WqkvT, Qb, Kb, Vb, nullptr, tbl);

    attn_mfma4_k<<<dim3(16, KVH_, B_), 512, 0, stream>>>(Qb, Kb, Vb, attn);

    gemm_bf16_k<1><<<dim3(16, 32), 256, 0, stream>>>(attn, WoT, nullptr, nullptr, nullptr, out, nullptr);
}

// Round 6
// 208.871 us; speedup vs baseline: 8.1875x; 1.2396x over previous
//
#include <hip/hip_runtime.h>
#include <hip/hip_bf16.h>
#include <cstdint>

#define B_ 2
#define S_ 2048
#define E_ 2048
#define H_ 32
#define KVH_ 8
#define D_ 64

typedef __bf16 bf16;
typedef __bf16 bf16x4 __attribute__((ext_vector_type(4)));
typedef __bf16 bf16x8 __attribute__((ext_vector_type(8)));
typedef float f32x4 __attribute__((ext_vector_type(4)));

// ---------------- cast x (f32) -> bf16 ----------------
__global__ __launch_bounds__(256) void cast_f32_bf16_k(const float* __restrict__ src,
                                                       bf16* __restrict__ dst, int n) {
    int i = (blockIdx.x * 256 + threadIdx.x) * 4;
    if (i < n) {
        f32x4 v = *(const f32x4*)(src + i);
        bf16x4 o;
        o[0] = (bf16)v[0]; o[1] = (bf16)v[1]; o[2] = (bf16)v[2]; o[3] = (bf16)v[3];
        *(bf16x4*)(dst + i) = o;
    }
}

// ---------------- transpose + cast: src f32 [R][C] -> dst bf16 [C][R], R==2048 ----------------
__global__ __launch_bounds__(256) void transpose_cast_k(const float* __restrict__ src,
                                                        bf16* __restrict__ dst, int C) {
    __shared__ float tile[32][33];
    int c0 = blockIdx.x * 32, r0 = blockIdx.y * 32;
    int tx = threadIdx.x, ty = threadIdx.y;  // (32, 8)
#pragma unroll
    for (int i = 0; i < 4; i++)
        tile[ty + 8 * i][tx] = src[(size_t)(r0 + ty + 8 * i) * C + c0 + tx];
    __syncthreads();
#pragma unroll
    for (int i = 0; i < 4; i++)
        dst[(size_t)(c0 + ty + 8 * i) * 2048 + r0 + tx] = (bf16)tile[tx][ty + 8 * i];
}

// ---------------- RoPE cos/sin table: tbl[(s*32+dp)*2] = {cos, sin} ----------------
__global__ __launch_bounds__(256) void rope_table_k(float* __restrict__ tbl) {
    int t = blockIdx.x * 256 + threadIdx.x;  // S_*32 threads
    int dp = t & 31, s = t >> 5;
    float invf = exp2f(-(float)dp * (13.287712379549449f / 32.0f));  // 10000^(-dp/32)
    float ang = (float)s * invf;
    tbl[t * 2] = cosf(ang);
    tbl[t * 2 + 1] = sinf(ang);
}

// ---------------- async global->LDS 16B helper (m97 pattern) ----------------
__device__ __forceinline__ void gload16(const bf16* g, bf16* l) {
    __builtin_amdgcn_global_load_lds((const __attribute__((address_space(1))) uint32_t*)g,
                                     (__attribute__((address_space(3))) uint32_t*)l, 16, 0, 0);
}

// ---------------- bf16 MFMA GEMM: C[M][N] = A[M][2048] * Bt[N][2048]^T ----------------
// BK=64, global_load_lds staging, linear LDS [128][64] with T2 both-sides XOR swizzle
// (rule 21: linear dest + inverse-swizzled SOURCE col + XOR on ds_read), 2-barrier loop,
// XCD swizzle. MODE 0: fused RoPE on Q/K cols; scatter Q/K, V transposed. MODE 1: f32 out.
template <int MODE>
__global__ __launch_bounds__(256, 3) void gemm_bf16_k(const bf16* __restrict__ A,
                                                      const bf16* __restrict__ Bt,
                                                      bf16* __restrict__ Q, bf16* __restrict__ Kb,
                                                      bf16* __restrict__ Vb, float* __restrict__ Cf,
                                                      const float* __restrict__ tbl) {
    __shared__ bf16 As[128 * 64];
    __shared__ bf16 Bs[128 * 64];
    const int t = threadIdx.x;
    const int lane = t & 63, w = t >> 6;
    const int wm = w >> 1, wn = w & 1;
    const int g = lane >> 4, l15 = lane & 15;
    // XCD-aware swizzle (nwg % 8 == 0 for both call sites)
    const int flat = blockIdx.x + gridDim.x * blockIdx.y;
    const int cpx = (gridDim.x * gridDim.y) >> 3;
    const int swz = (flat & 7) * cpx + (flat >> 3);
    const int m0 = (swz / gridDim.x) * 128, n0 = (swz % gridDim.x) * 128;

    f32x4 acc[4][4];
#pragma unroll
    for (int i = 0; i < 4; i++)
#pragma unroll
        for (int j = 0; j < 4; j++) acc[i][j] = f32x4{0.f, 0.f, 0.f, 0.f};

    // staging: wave w covers rows w*32 + i*8 + (lane>>3), source col pre-inverse-swizzled
    const int lrow = lane >> 3;                    // 0..7
    const int lcol = ((lane & 7) ^ lrow) * 8;      // involution within the 64-elem row
    const bf16* ga = A + (size_t)(m0 + w * 32 + lrow) * 2048 + lcol;
    const bf16* gb = Bt + (size_t)(n0 + w * 32 + lrow) * 2048 + lcol;
    bf16* la = As + w * 2048;  // wave-uniform LDS dest; HW adds lane*16B
    bf16* lb = Bs + w * 2048;

    const int rxor = (l15 & 7) * 8;  // read-side XOR (elems)

    for (int k0 = 0; k0 < 2048; k0 += 64) {
        __syncthreads();  // everyone done reading LDS of prev step
#pragma unroll
        for (int i = 0; i < 4; i++) {
            gload16(ga + k0 + (size_t)i * 8 * 2048, la + i * 512);
            gload16(gb + k0 + (size_t)i * 8 * 2048, lb + i * 512);
        }
        __syncthreads();  // vmcnt(0) drain + visibility
        bf16x8 af[4][2], bfr[4][2];
#pragma unroll
        for (int i = 0; i < 4; i++)
#pragma unroll
            for (int ks = 0; ks < 2; ks++) {
                const int coff = (ks * 32 + g * 8) ^ rxor;
                af[i][ks] = *(const bf16x8*)(As + (wm * 64 + i * 16 + l15) * 64 + coff);
                bfr[i][ks] = *(const bf16x8*)(Bs + (wn * 64 + i * 16 + l15) * 64 + coff);
            }
#pragma unroll
        for (int ks = 0; ks < 2; ks++)
#pragma unroll
            for (int i = 0; i < 4; i++)
#pragma unroll
                for (int j = 0; j < 4; j++)
                    acc[i][j] = __builtin_amdgcn_mfma_f32_16x16x32_bf16(af[i][ks], bfr[j][ks],
                                                                        acc[i][j], 0, 0, 0);
    }

    const int nbase = n0 + wn * 64;  // 64-aligned => whole j-span is one head/region
#pragma unroll
    for (int i = 0; i < 4; i++) {
        int mB = m0 + wm * 64 + i * 16 + g * 4;
        int b = mB >> 11, s = mB & 2047;
        if constexpr (MODE == 0) {
            if (nbase < 2560) {
                // fused RoPE on columns: pairs (j, j+2) == dims (d, d+32), d = j*16+l15
#pragma unroll
                for (int jh = 0; jh < 2; jh++) {
                    int dp = jh * 16 + l15;
#pragma unroll
                    for (int r = 0; r < 4; r++) {
                        const float* cs = tbl + ((size_t)(s + r) * 32 + dp) * 2;
                        float cv = cs[0], sv = cs[1];
                        float lo = acc[i][jh][r], hi = acc[i][jh + 2][r];
                        acc[i][jh][r] = lo * cv - hi * sv;
                        acc[i][jh + 2][r] = lo * sv + hi * cv;
                    }
                }
            }
        }
#pragma unroll
        for (int j = 0; j < 4; j++) {
            int n = nbase + j * 16 + l15;
            f32x4 v = acc[i][j];
            if constexpr (MODE == 0) {
                if (n < 2048) {
                    bf16* dst = Q + (((size_t)b * H_ + (n >> 6)) * S_ + s) * D_ + (n & 63);
#pragma unroll
                    for (int r = 0; r < 4; r++) dst[r * 64] = (bf16)v[r];
                } else if (n < 2560) {
                    bf16* dst = Kb + (((size_t)b * KVH_ + ((n - 2048) >> 6)) * S_ + s) * D_ + (n & 63);
#pragma unroll
                    for (int r = 0; r < 4; r++) dst[r * 64] = (bf16)v[r];
                } else {
                    // V transposed: [b][kvh][d=64][s=2048]
                    int vh = (n - 2560) >> 6, d = n & 63;
                    bf16* dst = Vb + (((size_t)b * KVH_ + vh) * 64 + d) * 2048 + s;
                    bf16x4 o;
#pragma unroll
                    for (int r = 0; r < 4; r++) o[r] = (bf16)v[r];
                    *(bf16x4*)dst = o;
                }
            } else {
#pragma unroll
                for (int r = 0; r < 4; r++) Cf[(size_t)(mB + r) * 2048 + n] = v[r];
            }
        }
    }
}

// ---------------- MFMA flash attention v4: GQA 4-head blocks, 8 waves ----------------
// Grid (16, KVH, B) = 256 blocks = 1/CU, all resident. Block = 512 thr = 8 waves.
// Wave w: head hh=w>>1, half u=w&1. Covers chunks C0=c and C1=31-c.
// S^T = mfma(K_frag, Q_frag*SC); O^T = mfma(V^T_frag, P_frag), shared k-perm (exact).
__global__ __launch_bounds__(512, 2) void attn_mfma4_k(const bf16* __restrict__ Q,
                                                       const bf16* __restrict__ Kb,
                                                       const bf16* __restrict__ Vtg,
                                                       bf16* __restrict__ Out) {
    __shared__ bf16 Ks[64 * 72];
    __shared__ bf16 Vts[64 * 72];
    const int t = threadIdx.x;
    const int w = t >> 6, lane = t & 63, g = lane >> 4, l15 = lane & 15;
    const int hh = w >> 1, u = w & 1;
    const int kvh = blockIdx.y, b = blockIdx.z;
    const int h = kvh * 4 + hh;
    const int c = blockIdx.x;  // pair id 0..15; chunks c and 31-c
    const int qb[2] = {c * 64 + u * 32, (31 - c) * 64 + u * 32};
    const int nt = 32 - c;

    const bf16* qbase = Q + ((size_t)b * H_ + h) * (size_t)(S_ * D_);
    const bf16* kbase = Kb + ((size_t)b * KVH_ + kvh) * (size_t)(S_ * D_);
    const bf16* vtbase = Vtg + ((size_t)b * KVH_ + kvh) * (size_t)(S_ * D_);

    const float SC = 0.18033688011112042f;  // log2(e)/8, folded into Q frags

    // Q fragments (B-operand layout, q = col = l15), pre-scaled by SC
    bf16x8 qf[2][2][2];  // [cidx][f][ks]
#pragma unroll
    for (int cidx = 0; cidx < 2; cidx++)
#pragma unroll
        for (int f = 0; f < 2; f++)
#pragma unroll
            for (int ks = 0; ks < 2; ks++) {
                bf16x8 raw = *(const bf16x8*)(qbase + (size_t)(qb[cidx] + f * 16 + l15) * 64 +
                                              ks * 32 + g * 8);
                bf16x8 sc8;
#pragma unroll
                for (int e = 0; e < 8; e++) sc8[e] = (bf16)((float)raw[e] * SC);
                qf[cidx][f][ks] = sc8;
            }

    f32x4 accO[4][2][2];  // [df][cidx][f]: O^T rows d=df*16+g*4+r, col q=l15
    float m_[2][2], l_[2][2];
#pragma unroll
    for (int cidx = 0; cidx < 2; cidx++)
#pragma unroll
        for (int f = 0; f < 2; f++) {
            m_[cidx][f] = -1e30f;
            l_[cidx][f] = 0.f;
#pragma unroll
            for (int df = 0; df < 4; df++) accO[df][cidx][f] = f32x4{0.f, 0.f, 0.f, 0.f};
        }

    const int row0 = t >> 3;          // 0..63 (512 threads cover the whole tile)
    const int ch0 = (t & 7) * 8;

    bf16x8 kA, vA;
#define LOADT(J0)                                                     \
    kA = *(const bf16x8*)(kbase + (size_t)((J0) + row0) * 64 + ch0);  \
    vA = *(const bf16x8*)(vtbase + (size_t)row0 * 2048 + (J0) + ch0);

    LOADT(0)
    for (int ti = 0; ti < nt; ti++) {
        const int j0 = ti * 64;
        __syncthreads();  // all waves done reading LDS (prev tile)
        *(bf16x8*)(Ks + row0 * 72 + ch0) = kA;
        *(bf16x8*)(Vts + row0 * 72 + ch0) = vA;
        __syncthreads();  // staged data visible
        if (ti + 1 < nt) { LOADT(j0 + 64) }  // prefetch hides under compute

        // --- K frags (shared by all 4 units of this wave)
        bf16x8 kf[4][2];
#pragma unroll
        for (int nf = 0; nf < 4; nf++)
#pragma unroll
            for (int ks = 0; ks < 2; ks++)
                kf[nf][ks] = *(const bf16x8*)(Ks + (nf * 16 + l15) * 72 + ks * 32 + g * 8);

#pragma unroll
        for (int cidx = 0; cidx < 2; cidx++) {
            if (cidx == 0 && ti > c) continue;  // low chunk fully done
            bf16x8 pb[2][2];  // [f][kslot]
#pragma unroll
            for (int f = 0; f < 2; f++) {
                f32x4 st[4];
                __builtin_amdgcn_s_setprio(1);
#pragma unroll
                for (int nf = 0; nf < 4; nf++) {
                    st[nf] = f32x4{0.f, 0.f, 0.f, 0.f};
#pragma unroll
                    for (int ks = 0; ks < 2; ks++)
                        st[nf] = __builtin_amdgcn_mfma_f32_16x16x32_bf16(kf[nf][ks],
                                                                         qf[cidx][f][ks],
                                                                         st[nf], 0, 0, 0);
                }
                __builtin_amdgcn_s_setprio(0);
                const int qrow0 = qb[cidx] + f * 16;
                const int q = qrow0 + l15;
                float sv[4][4];
                if (j0 + 63 > qrow0) {  // diagonal tile: mask
#pragma unroll
                    for (int nf = 0; nf < 4; nf++)
#pragma unroll
                        for (int r = 0; r < 4; r++)
                            sv[nf][r] = (j0 + nf * 16 + g * 4 + r > q) ? -1e30f : st[nf][r];
                } else {
#pragma unroll
                    for (int nf = 0; nf < 4; nf++)
#pragma unroll
                        for (int r = 0; r < 4; r++) sv[nf][r] = st[nf][r];
                }
                // row max: tree in-lane, then cross-g
                float m01, m23, mx;
                m01 = fmaxf(fmaxf(sv[0][0], sv[0][1]), fmaxf(sv[0][2], sv[0][3]));
                m23 = fmaxf(fmaxf(sv[1][0], sv[1][1]), fmaxf(sv[1][2], sv[1][3]));
                mx = fmaxf(m01, m23);
                m01 = fmaxf(fmaxf(sv[2][0], sv[2][1]), fmaxf(sv[2][2], sv[2][3]));
                m23 = fmaxf(fmaxf(sv[3][0], sv[3][1]), fmaxf(sv[3][2], sv[3][3]));
                mx = fmaxf(mx, fmaxf(m01, m23));
                mx = fmaxf(mx, __shfl_xor(mx, 16));
                mx = fmaxf(mx, __shfl_xor(mx, 32));
                // defer-max (T13): only rescale when max grew by > 8 (log2 domain)
                if (!__all(mx - m_[cidx][f] <= 8.f)) {
                    const float mn = fmaxf(m_[cidx][f], mx);
                    const float corr = exp2f(m_[cidx][f] - mn);
                    m_[cidx][f] = mn;
                    l_[cidx][f] *= corr;
#pragma unroll
                    for (int df = 0; df < 4; df++)
#pragma unroll
                        for (int r = 0; r < 4; r++) accO[df][cidx][f][r] *= corr;
                }
                const float mcur = m_[cidx][f];
                float p[4][4];
                float ssum = 0.f;
#pragma unroll
                for (int nf = 0; nf < 4; nf++)
#pragma unroll
                    for (int r = 0; r < 4; r++) {
                        p[nf][r] = exp2f(sv[nf][r] - mcur);
                        ssum += p[nf][r];
                    }
                ssum += __shfl_xor(ssum, 16);
                ssum += __shfl_xor(ssum, 32);
                l_[cidx][f] += ssum;
                // pack P to bf16 B-frags: e=nfp*4+r  <->  kv=kslot*32+nfp*16+g*4+r
#pragma unroll
                for (int kslot = 0; kslot < 2; kslot++)
#pragma unroll
                    for (int nfp = 0; nfp < 2; nfp++)
#pragma unroll
                        for (int r = 0; r < 4; r++)
                            pb[f][kslot][nfp * 4 + r] = (bf16)p[kslot * 2 + nfp][r];
            }

            // --- PV for this chunk: O^T += V^T_frag * P_frag (same k-perm on A side)
            __builtin_amdgcn_s_setprio(1);
#pragma unroll
            for (int df = 0; df < 4; df++) {
                const bf16* vrow = Vts + (df * 16 + l15) * 72;
#pragma unroll
                for (int kslot = 0; kslot < 2; kslot++) {
                    bf16x4 lo = *(const bf16x4*)(vrow + kslot * 32 + g * 4);
                    bf16x4 hi = *(const bf16x4*)(vrow + kslot * 32 + 16 + g * 4);
                    bf16x8 va = __builtin_shufflevector(lo, hi, 0, 1, 2, 3, 4, 5, 6, 7);
#pragma unroll
                    for (int f = 0; f < 2; f++)
                        accO[df][cidx][f] = __builtin_amdgcn_mfma_f32_16x16x32_bf16(
                            va, pb[f][kslot], accO[df][cidx][f], 0, 0, 0);
                }
            }
            __builtin_amdgcn_s_setprio(0);
        }
    }
#undef LOADT

    // --- epilogue: lane holds O^T[d=df*16+g*4+r][q=qb[cidx]+f*16+l15]
#pragma unroll
    for (int cidx = 0; cidx < 2; cidx++)
#pragma unroll
        for (int f = 0; f < 2; f++) {
            const float inv = 1.f / l_[cidx][f];
            const int s = qb[cidx] + f * 16 + l15;
            bf16* obase = Out + ((size_t)(b * S_ + s)) * 2048 + h * 64 + g * 4;
#pragma unroll
            for (int df = 0; df < 4; df++) {
                bf16x4 o;
#pragma unroll
                for (int r = 0; r < 4; r++) o[r] = (bf16)(accO[df][cidx][f][r] * inv);
                *(bf16x4*)(obase + df * 16) = o;
            }
        }
}

extern "C" void kernel_launch(void* const* d_in, const int* in_sizes, int n_in,
                              void* d_out, int out_size, void* d_ws, size_t ws_size,
                              hipStream_t stream) {
    const float* x = (const float*)d_in[0];
    const float* Wq = (const float*)d_in[1];
    const float* Wk = (const float*)d_in[2];
    const float* Wv = (const float*)d_in[3];
    const float* Wo = (const float*)d_in[4];
    float* out = (float*)d_out;

    char* ws = (char*)d_ws;
    size_t off = 0;
    auto alloc = [&](size_t bytes) {
        void* p = ws + off;
        off += (bytes + 255) & ~(size_t)255;
        return p;
    };
    bf16* xb = (bf16*)alloc((size_t)4096 * 2048 * 2);
    bf16* WqkvT = (bf16*)alloc((size_t)3072 * 2048 * 2);
    bf16* WoT = (bf16*)alloc((size_t)2048 * 2048 * 2);
    bf16* Qb = (bf16*)alloc((size_t)B_ * H_ * S_ * D_ * 2);
    bf16* Kb = (bf16*)alloc((size_t)B_ * KVH_ * S_ * D_ * 2);
    bf16* Vb = (bf16*)alloc((size_t)B_ * KVH_ * S_ * D_ * 2);  // transposed [b][kvh][d][s]
    float* tbl = (float*)alloc((size_t)S_ * 32 * 2 * sizeof(float));
    bf16* attn = xb;  // alias: xb dead after QKV GEMM

    cast_f32_bf16_k<<<8192, 256, 0, stream>>>(x, xb, 4096 * 2048);
    dim3 tb(32, 8);
    transpose_cast_k<<<dim3(64, 64), tb, 0, stream>>>(Wq, WqkvT, 2048);
    transpose_cast_k<<<dim3(16, 64), tb, 0, stream>>>(Wk, WqkvT + (size_t)2048 * 2048, 512);
    transpose_cast_k<<<dim3(16, 64), tb, 0, stream>>>(Wv, WqkvT + (size_t)2560 * 2048, 512);
    transpose_cast_k<<<dim3(64, 64), tb, 0, stream>>>(Wo, WoT, 2048);
    rope_table_k<<<256, 256, 0, stream>>>(tbl);

    // QKV GEMM with fused RoPE (needs tbl)
    gemm_bf16_k<0><<<dim3(24, 32), 256, 0, stream>>>(xb, WqkvT, Qb, Kb, Vb, nullptr, tbl);

    attn_mfma4_k<<<dim3(16, KVH_, B_), 512, 0, stream>>>(Qb, Kb, Vb, attn);

    gemm_bf16_k<1><<<dim3(16, 32), 256, 0, stream>>>(attn, WoT, nullptr, nullptr, nullptr, out, nullptr);
}

// Round 7
// 203.858 us; speedup vs baseline: 8.3889x; 1.0246x over previous
//
#include <hip/hip_runtime.h>
#include <hip/hip_bf16.h>
#include <cstdint>

#define B_ 2
#define S_ 2048
#define E_ 2048
#define H_ 32
#define KVH_ 8
#define D_ 64

typedef __bf16 bf16;
typedef __bf16 bf16x4 __attribute__((ext_vector_type(4)));
typedef __bf16 bf16x8 __attribute__((ext_vector_type(8)));
typedef float f32x4 __attribute__((ext_vector_type(4)));

// ---------------- cast x (f32) -> bf16 ----------------
__global__ __launch_bounds__(256) void cast_f32_bf16_k(const float* __restrict__ src,
                                                       bf16* __restrict__ dst, int n) {
    int i = (blockIdx.x * 256 + threadIdx.x) * 4;
    if (i < n) {
        f32x4 v = *(const f32x4*)(src + i);
        bf16x4 o;
        o[0] = (bf16)v[0]; o[1] = (bf16)v[1]; o[2] = (bf16)v[2]; o[3] = (bf16)v[3];
        *(bf16x4*)(dst + i) = o;
    }
}

// ---------------- fused transpose+cast for all 4 weights ----------------
// z=0: Wq->WqkvT[0], z=1: Wk->WqkvT+2048*2048, z=2: Wv->WqkvT+2560*2048, z=3: Wo->WoT
__global__ __launch_bounds__(256) void transpose_cast4_k(const float* __restrict__ Wq,
                                                         const float* __restrict__ Wk,
                                                         const float* __restrict__ Wv,
                                                         const float* __restrict__ Wo,
                                                         bf16* __restrict__ WqkvT,
                                                         bf16* __restrict__ WoT) {
    __shared__ float tile[32][33];
    const int z = blockIdx.z;
    const float* src;
    bf16* dst;
    int C;
    if (z == 0)      { src = Wq; dst = WqkvT;                          C = 2048; }
    else if (z == 1) { src = Wk; dst = WqkvT + (size_t)2048 * 2048;    C = 512;  }
    else if (z == 2) { src = Wv; dst = WqkvT + (size_t)2560 * 2048;    C = 512;  }
    else             { src = Wo; dst = WoT;                            C = 2048; }
    int c0 = blockIdx.x * 32, r0 = blockIdx.y * 32;
    if (c0 >= C) return;
    int tx = threadIdx.x, ty = threadIdx.y;  // (32, 8)
#pragma unroll
    for (int i = 0; i < 4; i++)
        tile[ty + 8 * i][tx] = src[(size_t)(r0 + ty + 8 * i) * C + c0 + tx];
    __syncthreads();
#pragma unroll
    for (int i = 0; i < 4; i++)
        dst[(size_t)(c0 + ty + 8 * i) * 2048 + r0 + tx] = (bf16)tile[tx][ty + 8 * i];
}

// ---------------- RoPE cos/sin table: tbl[(s*32+dp)*2] = {cos, sin} ----------------
__global__ __launch_bounds__(256) void rope_table_k(float* __restrict__ tbl) {
    int t = blockIdx.x * 256 + threadIdx.x;  // S_*32 threads
    int dp = t & 31, s = t >> 5;
    float invf = exp2f(-(float)dp * (13.287712379549449f / 32.0f));  // 10000^(-dp/32)
    float ang = (float)s * invf;
    tbl[t * 2] = cosf(ang);
    tbl[t * 2 + 1] = sinf(ang);
}

// ---------------- async global->LDS 16B helper (m97 pattern) ----------------
__device__ __forceinline__ void gload16(const bf16* g, bf16* l) {
    __builtin_amdgcn_global_load_lds((const __attribute__((address_space(1))) uint32_t*)g,
                                     (__attribute__((address_space(3))) uint32_t*)l, 16, 0, 0);
}

// ---------------- bf16 MFMA GEMM: C[M][N] = A[M][2048] * Bt[N][2048]^T ----------------
// BK=64, global_load_lds staging, linear LDS [128][64] with T2 both-sides XOR swizzle,
// 2-barrier loop, XCD swizzle. MODE 0: fused RoPE; scatter Q/K, V transposed. MODE 1: f32 out.
template <int MODE>
__global__ __launch_bounds__(256, 3) void gemm_bf16_k(const bf16* __restrict__ A,
                                                      const bf16* __restrict__ Bt,
                                                      bf16* __restrict__ Q, bf16* __restrict__ Kb,
                                                      bf16* __restrict__ Vb, float* __restrict__ Cf,
                                                      const float* __restrict__ tbl) {
    __shared__ bf16 As[128 * 64];
    __shared__ bf16 Bs[128 * 64];
    const int t = threadIdx.x;
    const int lane = t & 63, w = t >> 6;
    const int wm = w >> 1, wn = w & 1;
    const int g = lane >> 4, l15 = lane & 15;
    // XCD-aware swizzle (nwg % 8 == 0 for both call sites)
    const int flat = blockIdx.x + gridDim.x * blockIdx.y;
    const int cpx = (gridDim.x * gridDim.y) >> 3;
    const int swz = (flat & 7) * cpx + (flat >> 3);
    const int m0 = (swz / gridDim.x) * 128, n0 = (swz % gridDim.x) * 128;

    f32x4 acc[4][4];
#pragma unroll
    for (int i = 0; i < 4; i++)
#pragma unroll
        for (int j = 0; j < 4; j++) acc[i][j] = f32x4{0.f, 0.f, 0.f, 0.f};

    // staging: wave w covers rows w*32 + i*8 + (lane>>3), source col pre-inverse-swizzled
    const int lrow = lane >> 3;                    // 0..7
    const int lcol = ((lane & 7) ^ lrow) * 8;      // involution within the 64-elem row
    const bf16* ga = A + (size_t)(m0 + w * 32 + lrow) * 2048 + lcol;
    const bf16* gb = Bt + (size_t)(n0 + w * 32 + lrow) * 2048 + lcol;
    bf16* la = As + w * 2048;  // wave-uniform LDS dest; HW adds lane*16B
    bf16* lb = Bs + w * 2048;

    const int rxor = (l15 & 7) * 8;  // read-side XOR (elems)

    for (int k0 = 0; k0 < 2048; k0 += 64) {
        __syncthreads();  // everyone done reading LDS of prev step
#pragma unroll
        for (int i = 0; i < 4; i++) {
            gload16(ga + k0 + (size_t)i * 8 * 2048, la + i * 512);
            gload16(gb + k0 + (size_t)i * 8 * 2048, lb + i * 512);
        }
        __syncthreads();  // vmcnt(0) drain + visibility
        bf16x8 af[4][2], bfr[4][2];
#pragma unroll
        for (int i = 0; i < 4; i++)
#pragma unroll
            for (int ks = 0; ks < 2; ks++) {
                const int coff = (ks * 32 + g * 8) ^ rxor;
                af[i][ks] = *(const bf16x8*)(As + (wm * 64 + i * 16 + l15) * 64 + coff);
                bfr[i][ks] = *(const bf16x8*)(Bs + (wn * 64 + i * 16 + l15) * 64 + coff);
            }
#pragma unroll
        for (int ks = 0; ks < 2; ks++)
#pragma unroll
            for (int i = 0; i < 4; i++)
#pragma unroll
                for (int j = 0; j < 4; j++)
                    acc[i][j] = __builtin_amdgcn_mfma_f32_16x16x32_bf16(af[i][ks], bfr[j][ks],
                                                                        acc[i][j], 0, 0, 0);
    }

    const int nbase = n0 + wn * 64;  // 64-aligned => whole j-span is one head/region
#pragma unroll
    for (int i = 0; i < 4; i++) {
        int mB = m0 + wm * 64 + i * 16 + g * 4;
        int b = mB >> 11, s = mB & 2047;
        if constexpr (MODE == 0) {
            if (nbase < 2560) {
                // fused RoPE on columns: pairs (j, j+2) == dims (d, d+32), d = j*16+l15
#pragma unroll
                for (int jh = 0; jh < 2; jh++) {
                    int dp = jh * 16 + l15;
#pragma unroll
                    for (int r = 0; r < 4; r++) {
                        const float* cs = tbl + ((size_t)(s + r) * 32 + dp) * 2;
                        float cv = cs[0], sv = cs[1];
                        float lo = acc[i][jh][r], hi = acc[i][jh + 2][r];
                        acc[i][jh][r] = lo * cv - hi * sv;
                        acc[i][jh + 2][r] = lo * sv + hi * cv;
                    }
                }
            }
        }
#pragma unroll
        for (int j = 0; j < 4; j++) {
            int n = nbase + j * 16 + l15;
            f32x4 v = acc[i][j];
            if constexpr (MODE == 0) {
                if (n < 2048) {
                    bf16* dst = Q + (((size_t)b * H_ + (n >> 6)) * S_ + s) * D_ + (n & 63);
#pragma unroll
                    for (int r = 0; r < 4; r++) dst[r * 64] = (bf16)v[r];
                } else if (n < 2560) {
                    bf16* dst = Kb + (((size_t)b * KVH_ + ((n - 2048) >> 6)) * S_ + s) * D_ + (n & 63);
#pragma unroll
                    for (int r = 0; r < 4; r++) dst[r * 64] = (bf16)v[r];
                } else {
                    // V transposed: [b][kvh][d=64][s=2048]
                    int vh = (n - 2560) >> 6, d = n & 63;
                    bf16* dst = Vb + (((size_t)b * KVH_ + vh) * 64 + d) * 2048 + s;
                    bf16x4 o;
#pragma unroll
                    for (int r = 0; r < 4; r++) o[r] = (bf16)v[r];
                    *(bf16x4*)dst = o;
                }
            } else {
#pragma unroll
                for (int r = 0; r < 4; r++) Cf[(size_t)(mB + r) * 2048 + n] = v[r];
            }
        }
    }
}

// ---------------- MFMA flash attention v5: 32-row pairs, 2 blocks/CU ----------------
// Grid (32, KVH, B) = 512 blocks = 2/CU. Block = 512 thr = 8 waves.
// Pair id c: 32-row chunks c and 63-c. Wave w: head hh=w>>1, half u=w&1;
// owns 16-row frags at qrow = 32c+16u and 32(63-c)+16u. K/V staged once, shared by 4 heads.
// S^T = mfma(K_frag, Q_frag*SC); O^T = mfma(V^T_frag, P_frag), shared k-perm (exact).
__global__ __launch_bounds__(512, 4) void attn_mfma5_k(const bf16* __restrict__ Q,
                                                       const bf16* __restrict__ Kb,
                                                       const bf16* __restrict__ Vtg,
                                                       bf16* __restrict__ Out) {
    __shared__ bf16 Ks[64 * 72];
    __shared__ bf16 Vts[64 * 72];
    const int t = threadIdx.x;
    const int w = t >> 6, lane = t & 63, g = lane >> 4, l15 = lane & 15;
    const int hh = w >> 1, u = w & 1;
    const int kvh = blockIdx.y, b = blockIdx.z;
    const int h = kvh * 4 + hh;
    const int c = blockIdx.x;  // pair id 0..31; 32-row chunks c and 63-c
    const int qrow[2] = {c * 32 + u * 16, (63 - c) * 32 + u * 16};
    const int nt = ((2047 - 32 * c) >> 6) + 1;      // tiles for high chunk
    const int lowmax = (32 * c + 31) >> 6;          // last tile touching low chunk

    const bf16* qbase = Q + ((size_t)b * H_ + h) * (size_t)(S_ * D_);
    const bf16* kbase = Kb + ((size_t)b * KVH_ + kvh) * (size_t)(S_ * D_);
    const bf16* vtbase = Vtg + ((size_t)b * KVH_ + kvh) * (size_t)(S_ * D_);

    const float SC = 0.18033688011112042f;  // log2(e)/8, folded into Q frags

    // Q fragments (B-operand layout, q = col = l15), pre-scaled by SC
    bf16x8 qf[2][2];  // [cidx][ks]
#pragma unroll
    for (int cidx = 0; cidx < 2; cidx++)
#pragma unroll
        for (int ks = 0; ks < 2; ks++) {
            bf16x8 raw = *(const bf16x8*)(qbase + (size_t)(qrow[cidx] + l15) * 64 + ks * 32 + g * 8);
            bf16x8 sc8;
#pragma unroll
            for (int e = 0; e < 8; e++) sc8[e] = (bf16)((float)raw[e] * SC);
            qf[cidx][ks] = sc8;
        }

    f32x4 accO[4][2];  // [df][cidx]: O^T rows d=df*16+g*4+r, col q=l15
    float m_[2] = {-1e30f, -1e30f}, l_[2] = {0.f, 0.f};
#pragma unroll
    for (int df = 0; df < 4; df++)
#pragma unroll
        for (int cidx = 0; cidx < 2; cidx++) accO[df][cidx] = f32x4{0.f, 0.f, 0.f, 0.f};

    const int row0 = t >> 3;          // 0..63 (512 threads cover the whole tile)
    const int ch0 = (t & 7) * 8;

    bf16x8 kA, vA;
#define LOADT(J0)                                                     \
    kA = *(const bf16x8*)(kbase + (size_t)((J0) + row0) * 64 + ch0);  \
    vA = *(const bf16x8*)(vtbase + (size_t)row0 * 2048 + (J0) + ch0);

    LOADT(0)
    for (int ti = 0; ti < nt; ti++) {
        const int j0 = ti * 64;
        __syncthreads();  // all waves done reading LDS (prev tile)
        *(bf16x8*)(Ks + row0 * 72 + ch0) = kA;
        *(bf16x8*)(Vts + row0 * 72 + ch0) = vA;
        __syncthreads();  // staged data visible
        if (ti + 1 < nt) { LOADT(j0 + 64) }  // prefetch hides under compute

        // --- K frags (shared by both chunks)
        bf16x8 kf[4][2];
#pragma unroll
        for (int nf = 0; nf < 4; nf++)
#pragma unroll
            for (int ks = 0; ks < 2; ks++)
                kf[nf][ks] = *(const bf16x8*)(Ks + (nf * 16 + l15) * 72 + ks * 32 + g * 8);

#pragma unroll
        for (int cidx = 0; cidx < 2; cidx++) {
            if (cidx == 0 && ti > lowmax) continue;  // low chunk fully done
            f32x4 st[4];
            __builtin_amdgcn_s_setprio(1);
#pragma unroll
            for (int nf = 0; nf < 4; nf++) {
                st[nf] = f32x4{0.f, 0.f, 0.f, 0.f};
#pragma unroll
                for (int ks = 0; ks < 2; ks++)
                    st[nf] = __builtin_amdgcn_mfma_f32_16x16x32_bf16(kf[nf][ks], qf[cidx][ks],
                                                                     st[nf], 0, 0, 0);
            }
            __builtin_amdgcn_s_setprio(0);
            const int qrow0 = qrow[cidx];
            const int q = qrow0 + l15;
            float sv[4][4];
            if (j0 + 63 > qrow0) {  // diagonal tile: mask
#pragma unroll
                for (int nf = 0; nf < 4; nf++)
#pragma unroll
                    for (int r = 0; r < 4; r++)
                        sv[nf][r] = (j0 + nf * 16 + g * 4 + r > q) ? -1e30f : st[nf][r];
            } else {
#pragma unroll
                for (int nf = 0; nf < 4; nf++)
#pragma unroll
                    for (int r = 0; r < 4; r++) sv[nf][r] = st[nf][r];
            }
            // row max: tree in-lane, then cross-g
            float m01, m23, mx;
            m01 = fmaxf(fmaxf(sv[0][0], sv[0][1]), fmaxf(sv[0][2], sv[0][3]));
            m23 = fmaxf(fmaxf(sv[1][0], sv[1][1]), fmaxf(sv[1][2], sv[1][3]));
            mx = fmaxf(m01, m23);
            m01 = fmaxf(fmaxf(sv[2][0], sv[2][1]), fmaxf(sv[2][2], sv[2][3]));
            m23 = fmaxf(fmaxf(sv[3][0], sv[3][1]), fmaxf(sv[3][2], sv[3][3]));
            mx = fmaxf(mx, fmaxf(m01, m23));
            mx = fmaxf(mx, __shfl_xor(mx, 16));
            mx = fmaxf(mx, __shfl_xor(mx, 32));
            // defer-max (T13): only rescale when max grew by > 8 (log2 domain)
            if (!__all(mx - m_[cidx] <= 8.f)) {
                const float mn = fmaxf(m_[cidx], mx);
                const float corr = exp2f(m_[cidx] - mn);
                m_[cidx] = mn;
                l_[cidx] *= corr;
#pragma unroll
                for (int df = 0; df < 4; df++)
#pragma unroll
                    for (int r = 0; r < 4; r++) accO[df][cidx][r] *= corr;
            }
            const float mcur = m_[cidx];
            float p[4][4];
            float ssum = 0.f;
#pragma unroll
            for (int nf = 0; nf < 4; nf++)
#pragma unroll
                for (int r = 0; r < 4; r++) {
                    p[nf][r] = exp2f(sv[nf][r] - mcur);
                    ssum += p[nf][r];
                }
            ssum += __shfl_xor(ssum, 16);
            ssum += __shfl_xor(ssum, 32);
            l_[cidx] += ssum;
            // pack P to bf16 B-frags: e=nfp*4+r  <->  kv=kslot*32+nfp*16+g*4+r
            bf16x8 pb[2];
#pragma unroll
            for (int kslot = 0; kslot < 2; kslot++)
#pragma unroll
                for (int nfp = 0; nfp < 2; nfp++)
#pragma unroll
                    for (int r = 0; r < 4; r++)
                        pb[kslot][nfp * 4 + r] = (bf16)p[kslot * 2 + nfp][r];

            // --- PV: O^T += V^T_frag * P_frag (same k-perm on A side)
            __builtin_amdgcn_s_setprio(1);
#pragma unroll
            for (int df = 0; df < 4; df++) {
                const bf16* vrow = Vts + (df * 16 + l15) * 72;
#pragma unroll
                for (int kslot = 0; kslot < 2; kslot++) {
                    bf16x4 lo = *(const bf16x4*)(vrow + kslot * 32 + g * 4);
                    bf16x4 hi = *(const bf16x4*)(vrow + kslot * 32 + 16 + g * 4);
                    bf16x8 va = __builtin_shufflevector(lo, hi, 0, 1, 2, 3, 4, 5, 6, 7);
                    accO[df][cidx] = __builtin_amdgcn_mfma_f32_16x16x32_bf16(va, pb[kslot],
                                                                             accO[df][cidx], 0, 0, 0);
                }
            }
            __builtin_amdgcn_s_setprio(0);
        }
    }
#undef LOADT

    // --- epilogue: lane holds O^T[d=df*16+g*4+r][q=qrow[cidx]+l15]
#pragma unroll
    for (int cidx = 0; cidx < 2; cidx++) {
        const float inv = 1.f / l_[cidx];
        const int s = qrow[cidx] + l15;
        bf16* obase = Out + ((size_t)(b * S_ + s)) * 2048 + h * 64 + g * 4;
#pragma unroll
        for (int df = 0; df < 4; df++) {
            bf16x4 o;
#pragma unroll
            for (int r = 0; r < 4; r++) o[r] = (bf16)(accO[df][cidx][r] * inv);
            *(bf16x4*)(obase + df * 16) = o;
        }
    }
}

extern "C" void kernel_launch(void* const* d_in, const int* in_sizes, int n_in,
                              void* d_out, int out_size, void* d_ws, size_t ws_size,
                              hipStream_t stream) {
    const float* x = (const float*)d_in[0];
    const float* Wq = (const float*)d_in[1];
    const float* Wk = (const float*)d_in[2];
    const float* Wv = (const float*)d_in[3];
    const float* Wo = (const float*)d_in[4];
    float* out = (float*)d_out;

    char* ws = (char*)d_ws;
    size_t off = 0;
    auto alloc = [&](size_t bytes) {
        void* p = ws + off;
        off += (bytes + 255) & ~(size_t)255;
        return p;
    };
    bf16* xb = (bf16*)alloc((size_t)4096 * 2048 * 2);
    bf16* WqkvT = (bf16*)alloc((size_t)3072 * 2048 * 2);
    bf16* WoT = (bf16*)alloc((size_t)2048 * 2048 * 2);
    bf16* Qb = (bf16*)alloc((size_t)B_ * H_ * S_ * D_ * 2);
    bf16* Kb = (bf16*)alloc((size_t)B_ * KVH_ * S_ * D_ * 2);
    bf16* Vb = (bf16*)alloc((size_t)B_ * KVH_ * S_ * D_ * 2);  // transposed [b][kvh][d][s]
    float* tbl = (float*)alloc((size_t)S_ * 32 * 2 * sizeof(float));
    bf16* attn = xb;  // alias: xb dead after QKV GEMM

    cast_f32_bf16_k<<<8192, 256, 0, stream>>>(x, xb, 4096 * 2048);
    transpose_cast4_k<<<dim3(64, 64, 4), dim3(32, 8), 0, stream>>>(Wq, Wk, Wv, Wo, WqkvT, WoT);
    rope_table_k<<<256, 256, 0, stream>>>(tbl);

    // QKV GEMM with fused RoPE (needs tbl)
    gemm_bf16_k<0><<<dim3(24, 32), 256, 0, stream>>>(xb, WqkvT, Qb, Kb, Vb, nullptr, tbl);

    attn_mfma5_k<<<dim3(32, KVH_, B_), 512, 0, stream>>>(Qb, Kb, Vb, attn);

    gemm_bf16_k<1><<<dim3(16, 32), 256, 0, stream>>>(attn, WoT, nullptr, nullptr, nullptr, out, nullptr);
}